// Round 3
// baseline (676.808 us; speedup 1.0000x reference)
//
#include <hip/hip_runtime.h>
#include <hip/hip_bf16.h>
#include <stdint.h>

#define HIDDEN  1024
#define FFN     3584
#define NE      8
#define NTOK    2048
#define CAP     2048
#define OUT_ELEMS (NTOK * HIDDEN)   /* 2097152 */

/* ---- workspace layout (bytes) ---- */
#define X_OFF    0u                          /* x as bf16: 2048*1024*2 = 4 MiB   */
#define CNT_OFF  (4u*1024u*1024u)            /* 8 int counters                   */
#define TOK_OFF  (CNT_OFF + 256u)            /* token lists: 8*2048*4 = 64 KiB   */
#define WGT_OFF  (TOK_OFF + 65536u)          /* combine weights: 64 KiB          */
#define INV_OFF  (WGT_OFF + 65536u)          /* token -> 2 slot ids: 16 KiB      */
#define ACT_OFF  (INV_OFF + 16384u)          /* packed act bf16: 4096*3584*2     */
#define ACT_SZ   (4096u * 3584u * 2u)        /* 29360128                         */
#define WGU_OFF  (ACT_OFF + ACT_SZ)          /* bf16 tiled gate/up weights       */
#define WGU_SZ   (8u*56u*16u*16384u)         /* 117440512 (112 MiB)              */
#define WDB_OFF  (WGU_OFF + WGU_SZ)          /* bf16 tiled down weights          */
#define WDB_SZ   (8u*8u*56u*16384u)          /* 58720256 (56 MiB)                */
#define PART_OFF (WDB_OFF + WDB_SZ)          /* fp32 partial rows: 4096*1024*4   */
#define PART_SZ  (4096u*1024u*4u)            /* 16 MiB                           */
#define WS_NEED  ((size_t)PART_OFF + (size_t)PART_SZ)

typedef __attribute__((ext_vector_type(8))) short short8;
typedef __attribute__((ext_vector_type(4))) float floatx4;

static __device__ __forceinline__ uint32_t f2bf(float f) {
  union { float f; uint32_t u; } v; v.f = f;
  return (v.u + 0x7FFFu + ((v.u >> 16) & 1u)) >> 16;   /* RNE */
}
static __device__ __forceinline__ uint32_t pack2(float lo, float hi) {
  return f2bf(lo) | (f2bf(hi) << 16);
}
union S8U { uint4 u; short8 s; };
static __device__ __forceinline__ short8 as_short8(uint4 v) { S8U x; x.u = v; return x.s; }

/* async global -> LDS, 16B per lane; LDS dest is wave-uniform base + lane*16 */
static __device__ __forceinline__ void ld_g2l16(const void* g, void* l) {
  __builtin_amdgcn_global_load_lds(
      (const __attribute__((address_space(1))) void*)g,
      (__attribute__((address_space(3))) void*)l, 16, 0, 0);
}

/* stage one 16KB A-tile + 16KB B-tile into the given LDS buffers */
static __device__ __forceinline__ void stage_tile(
    const char* const* aptr, const char* bptr, size_t akt, size_t bkt,
    uint4* AsB, uint4* BsB, int w)
{
#pragma unroll
  for (int it = 0; it < 4; ++it)
    ld_g2l16(aptr[it] + akt, &AsB[(w * 4 + it) * 64]);
#pragma unroll
  for (int it = 0; it < 4; ++it)
    ld_g2l16(bptr + bkt + (size_t)it * 1024u, &BsB[(w * 4 + it) * 64]);
}

/* ---- zero output accumulation region + expert counters (fallback only) ---- */
__global__ __launch_bounds__(256) void moe_prep(float4* __restrict__ out4,
                                                int* __restrict__ cnt) {
  uint32_t i = blockIdx.x * 256u + threadIdx.x;
  out4[i] = make_float4(0.f, 0.f, 0.f, 0.f);
  if (blockIdx.x == 0 && threadIdx.x < NE) cnt[threadIdx.x] = 0;
}

/* ---- x fp32 -> bf16 (+ cnt zero for fast path) ---- */
__global__ __launch_bounds__(256) void moe_convert(const float4* __restrict__ x4,
                                                   uint4* __restrict__ xb,
                                                   int* __restrict__ cnt) {
  uint32_t g = blockIdx.x * 256u + threadIdx.x;
  float4 a = x4[2u*g], b = x4[2u*g + 1u];
  xb[g] = make_uint4(pack2(a.x, a.y), pack2(a.z, a.w),
                     pack2(b.x, b.y), pack2(b.z, b.w));
  if (blockIdx.x == 0 && threadIdx.x < NE) cnt[threadIdx.x] = 0;
}

/* ---- router: one wave per token ---- */
__global__ __launch_bounds__(256) void moe_router(
    const float* __restrict__ x, const float* __restrict__ gw,
    float* __restrict__ logits, int* __restrict__ cnt,
    int* __restrict__ tok, float* __restrict__ wgt, int* __restrict__ inv)
{
  const int t = blockIdx.x * 4 + (threadIdx.x >> 6);
  const int lane = threadIdx.x & 63;
  const float* xr = x + (size_t)t * HIDDEN;
  float a[NE];
#pragma unroll
  for (int e = 0; e < NE; ++e) a[e] = 0.f;
  for (int hh = 0; hh < HIDDEN / 64; ++hh) {
    float xv = xr[hh * 64 + lane];
#pragma unroll
    for (int e = 0; e < NE; ++e) a[e] += xv * gw[e * HIDDEN + hh * 64 + lane];
  }
#pragma unroll
  for (int off = 32; off > 0; off >>= 1) {
#pragma unroll
    for (int e = 0; e < NE; ++e) a[e] += __shfl_xor(a[e], off);
  }
  if (lane == 0) {
#pragma unroll
    for (int e = 0; e < NE; ++e) logits[t * NE + e] = a[e];
    int i0 = 0; float v0 = a[0];
#pragma unroll
    for (int e = 1; e < NE; ++e) if (a[e] > v0) { v0 = a[e]; i0 = e; }
    int i1 = (i0 == 0) ? 1 : 0; float v1 = a[i1];
#pragma unroll
    for (int e = 0; e < NE; ++e) if (e != i0 && a[e] > v1) { v1 = a[e]; i1 = e; }
    float w0 = 1.f / (1.f + __expf(v1 - v0));
    float w1 = 1.f - w0;
    int p0 = atomicAdd(&cnt[i0], 1); tok[i0 * CAP + p0] = t; wgt[i0 * CAP + p0] = w0;
    int p1 = atomicAdd(&cnt[i1], 1); tok[i1 * CAP + p1] = t; wgt[i1 * CAP + p1] = w1;
    inv[t * 2 + 0] = i0 * CAP + p0;
    inv[t * 2 + 1] = i1 * CAP + p1;
  }
}

/* ==== weight preconvert: fp32 -> bf16, GEMM-native swizzled tile layout ==== */
__global__ __launch_bounds__(256) void moe_wconv_gu(const float* __restrict__ wgu,
                                                    uint4* __restrict__ wgub) {
  const int kt = blockIdx.x, fb = blockIdx.y, e = blockIdx.z;
  const int f0 = fb * 64, k0 = kt * 64;
  const float* wB = wgu + (size_t)e * HIDDEN * (2 * FFN);
  uint4* dst = wgub + ((size_t)(e * 56 + fb) * 16 + kt) * 1024;
#pragma unroll
  for (int it = 0; it < 4; ++it) {
    int mid = it * 256 + threadIdx.x;
    int kp = mid >> 5;
    int n  = (mid & 31) * 4;
    int col = f0 + ((n >> 6) << 5) + (n & 31) + (((n >> 5) & 1) ? FFN : 0);
    const float* src = wB + (size_t)(k0 + 2 * kp) * (2 * FFN) + col;
    float4 r0 = *(const float4*)src;
    float4 r1 = *(const float4*)(src + 2 * FFN);
    dst[kp * 32 + ((n >> 2) ^ (((kp >> 2) & 1) << 2))] =
        make_uint4(pack2(r0.x, r1.x), pack2(r0.y, r1.y),
                   pack2(r0.z, r1.z), pack2(r0.w, r1.w));
  }
}

__global__ __launch_bounds__(256) void moe_wconv_d(const float* __restrict__ wd,
                                                   uint4* __restrict__ wdb) {
  const int kt = blockIdx.x, nb = blockIdx.y, e = blockIdx.z;
  const int n0 = nb * 128, k0 = kt * 64;
  const float* wB = wd + (size_t)e * FFN * HIDDEN;
  uint4* dst = wdb + ((size_t)(e * 8 + nb) * 56 + kt) * 1024;
#pragma unroll
  for (int it = 0; it < 4; ++it) {
    int mid = it * 256 + threadIdx.x;
    int kp = mid >> 5;
    int n  = (mid & 31) * 4;
    const float* src = wB + (size_t)(k0 + 2 * kp) * HIDDEN + n0 + n;
    float4 r0 = *(const float4*)src;
    float4 r1 = *(const float4*)(src + HIDDEN);
    dst[kp * 32 + ((n >> 2) ^ (((kp >> 2) & 1) << 2))] =
        make_uint4(pack2(r0.x, r1.x), pack2(r0.y, r1.y),
                   pack2(r0.z, r1.z), pack2(r0.w, r1.w));
  }
}

/* ==== grouped GEMM 1 (fast, 2-phase dbuf): act = silu(x@Wg)*(x@Wu) ==== */
__global__ __launch_bounds__(256) void moe_gateup(
    const uint4* __restrict__ xb, const uint4* __restrict__ wgub,
    const int* __restrict__ cnt, const int* __restrict__ tok,
    unsigned short* __restrict__ act)
{
  const int e  = blockIdx.z;
  const int m0 = blockIdx.y * 128;
  const int fb = blockIdx.x;
  const int f0 = fb * 64;
  const int cn = cnt[e];
  if (m0 >= cn) return;
  int basev = 0;
#pragma unroll
  for (int i = 0; i < NE; ++i) { int ci = cnt[i]; if (i < e) basev += ci; }

  __shared__ uint4 As[2][1024];
  __shared__ uint4 Bs4[2][1024];

  const int tid  = threadIdx.x;
  const int lane = tid & 63;
  const int w    = tid >> 6;
  const int wm   = w >> 1, wn = w & 1;
  const int q    = lane >> 4;
  const int c    = lane & 15;

  const int* tokE = tok + e * CAP;
  const char* aptr[4];
#pragma unroll
  for (int it = 0; it < 4; ++it) {
    int p   = (w * 4 + it) * 64 + lane;
    int row = p >> 3, c8 = p & 7;
    int mrow = m0 + row; if (mrow >= cn) mrow = cn - 1;
    aptr[it] = (const char*)(xb + (size_t)tokE[mrow] * (HIDDEN / 8) + (c8 ^ (row & 7)));
  }
  const char* bptr = (const char*)wgub + ((size_t)(e * 56 + fb) * 16) * 16384u
                   + (size_t)w * 4096u + (size_t)lane * 16u;

  floatx4 acc[4][4];
#pragma unroll
  for (int i = 0; i < 4; ++i)
#pragma unroll
    for (int j = 0; j < 4; ++j) acc[i][j] = (floatx4){0.f, 0.f, 0.f, 0.f};

  const int NT = HIDDEN / 64;
  stage_tile(aptr, bptr, 0, 0, As[0], Bs4[0], w);
  __syncthreads();
  int cur = 0;
  for (int kt = 0; kt < NT; ++kt) {
    if (kt + 1 < NT)
      stage_tile(aptr, bptr, (size_t)(kt + 1) * 128u, (size_t)(kt + 1) * 16384u,
                 As[cur ^ 1], Bs4[cur ^ 1], w);
    const uint4*    Asc = As[cur];
    const uint32_t* Bsc = (const uint32_t*)Bs4[cur];
#pragma unroll
    for (int ks = 0; ks < 2; ++ks) {
      short8 af[4];
#pragma unroll
      for (int i = 0; i < 4; ++i) {
        int row = wm * 64 + i * 16 + c;
        int kc8 = ks * 4 + q;
        af[i] = as_short8(Asc[row * 8 + (kc8 ^ (row & 7))]);
      }
      short8 bfr[4];
#pragma unroll
      for (int j = 0; j < 4; ++j) {
        int n  = wn * 64 + j * 16 + c;
        int kp = ks * 16 + q * 4;
        int nn = n ^ ((q & 1) << 4);
        bfr[j] = as_short8(make_uint4(Bsc[(kp + 0) * 128 + nn], Bsc[(kp + 1) * 128 + nn],
                                      Bsc[(kp + 2) * 128 + nn], Bsc[(kp + 3) * 128 + nn]));
      }
#pragma unroll
      for (int i = 0; i < 4; ++i)
#pragma unroll
        for (int j = 0; j < 4; ++j)
          acc[i][j] = __builtin_amdgcn_mfma_f32_16x16x32_bf16(af[i], bfr[j], acc[i][j], 0, 0, 0);
    }
    __syncthreads();    /* drains prefetch DMA + lgkm, releases both buffers */
    cur ^= 1;
  }

#pragma unroll
  for (int i = 0; i < 4; ++i) {
#pragma unroll
    for (int r = 0; r < 4; ++r) {
      int m = m0 + wm * 64 + i * 16 + q * 4 + r;
      if (m < cn) {
#pragma unroll
        for (int j = 0; j < 2; ++j) {
          float g = acc[i][j][r];
          float u = acc[i][j + 2][r];
          float a = (g / (1.f + __expf(-g))) * u;
          act[(size_t)(basev + m) * FFN + (f0 + wn * 32 + j * 16 + c)] = (unsigned short)f2bf(a);
        }
      }
    }
  }
}

/* ==== grouped GEMM 2 (fast, 2-phase dbuf): part = w * (act @ Wdown) ==== */
__global__ __launch_bounds__(256) void moe_down(
    const unsigned short* __restrict__ act, const uint4* __restrict__ wdb,
    const int* __restrict__ cnt, const int* __restrict__ tok,
    const float* __restrict__ wgt, float* __restrict__ part)
{
  const int e  = blockIdx.z;
  const int m0 = blockIdx.y * 128;
  const int nb = blockIdx.x;
  const int n0 = nb * 128;
  const int cn = cnt[e];
  if (m0 >= cn) return;
  int basev = 0;
#pragma unroll
  for (int i = 0; i < NE; ++i) { int ci = cnt[i]; if (i < e) basev += ci; }

  __shared__ uint4 As[2][1024];
  __shared__ uint4 Bs4[2][1024];

  const int tid  = threadIdx.x;
  const int lane = tid & 63;
  const int w    = tid >> 6;
  const int wm   = w >> 1, wn = w & 1;
  const int q    = lane >> 4;
  const int c    = lane & 15;

  const char* aptr[4];
#pragma unroll
  for (int it = 0; it < 4; ++it) {
    int p   = (w * 4 + it) * 64 + lane;
    int row = p >> 3, c8 = p & 7;
    int mrow = m0 + row; if (mrow >= cn) mrow = cn - 1;
    aptr[it] = (const char*)act +
               ((size_t)(basev + mrow) * FFN + (size_t)((c8 ^ (row & 7)) * 8)) * 2u;
  }
  const char* bptr = (const char*)wdb + ((size_t)(e * 8 + nb) * 56) * 16384u
                   + (size_t)w * 4096u + (size_t)lane * 16u;

  floatx4 acc[4][4];
#pragma unroll
  for (int i = 0; i < 4; ++i)
#pragma unroll
    for (int j = 0; j < 4; ++j) acc[i][j] = (floatx4){0.f, 0.f, 0.f, 0.f};

  const int NT = FFN / 64;
  stage_tile(aptr, bptr, 0, 0, As[0], Bs4[0], w);
  __syncthreads();
  int cur = 0;
  for (int kt = 0; kt < NT; ++kt) {
    if (kt + 1 < NT)
      stage_tile(aptr, bptr, (size_t)(kt + 1) * 128u, (size_t)(kt + 1) * 16384u,
                 As[cur ^ 1], Bs4[cur ^ 1], w);
    const uint4*    Asc = As[cur];
    const uint32_t* Bsc = (const uint32_t*)Bs4[cur];
#pragma unroll
    for (int ks = 0; ks < 2; ++ks) {
      short8 af[4];
#pragma unroll
      for (int i = 0; i < 4; ++i) {
        int row = wm * 64 + i * 16 + c;
        int kc8 = ks * 4 + q;
        af[i] = as_short8(Asc[row * 8 + (kc8 ^ (row & 7))]);
      }
      short8 bfr[4];
#pragma unroll
      for (int j = 0; j < 4; ++j) {
        int n  = wn * 64 + j * 16 + c;
        int kp = ks * 16 + q * 4;
        int nn = n ^ ((q & 1) << 4);
        bfr[j] = as_short8(make_uint4(Bsc[(kp + 0) * 128 + nn], Bsc[(kp + 1) * 128 + nn],
                                      Bsc[(kp + 2) * 128 + nn], Bsc[(kp + 3) * 128 + nn]));
      }
#pragma unroll
      for (int i = 0; i < 4; ++i)
#pragma unroll
        for (int j = 0; j < 4; ++j)
          acc[i][j] = __builtin_amdgcn_mfma_f32_16x16x32_bf16(af[i], bfr[j], acc[i][j], 0, 0, 0);
    }
    __syncthreads();
    cur ^= 1;
  }

  /* epilogue: scale by combine weight, PLAIN store to packed partial row */
#pragma unroll
  for (int i = 0; i < 4; ++i) {
#pragma unroll
    for (int r = 0; r < 4; ++r) {
      int m = m0 + wm * 64 + i * 16 + q * 4 + r;
      if (m < cn) {
        float  wg   = wgt[e * CAP + m];
        float* prow = part + (size_t)(basev + m) * HIDDEN + n0 + wn * 64 + c;
#pragma unroll
        for (int j = 0; j < 4; ++j)
          prow[j * 16] = acc[i][j][r] * wg;
      }
    }
  }
}

/* ==== combine: out[t] = part[slot0(t)] + part[slot1(t)] ==== */
__global__ __launch_bounds__(256) void moe_combine(
    const int* __restrict__ cnt, const int* __restrict__ inv,
    const float4* __restrict__ part4, float4* __restrict__ out4)
{
  const int t  = blockIdx.x;
  const int s0 = inv[2 * t], s1 = inv[2 * t + 1];
  const int e0 = s0 >> 11, e1 = s1 >> 11;          /* CAP = 2048 */
  int b0 = 0, b1 = 0;
#pragma unroll
  for (int i = 0; i < NE; ++i) {
    int ci = cnt[i];
    if (i < e0) b0 += ci;
    if (i < e1) b1 += ci;
  }
  const size_t r0 = (size_t)(b0 + (s0 & (CAP - 1))) * 256u;
  const size_t r1 = (size_t)(b1 + (s1 & (CAP - 1))) * 256u;
  const int i = threadIdx.x;
  float4 a = part4[r0 + i];
  float4 b = part4[r1 + i];
  out4[(size_t)t * 256u + i] = make_float4(a.x + b.x, a.y + b.y, a.z + b.z, a.w + b.w);
}

/* ==== legacy fallback GEMMs (used only if workspace too small) ==== */
__global__ __launch_bounds__(256) void moe_gateup_lg(
    const uint4* __restrict__ xb, const float* __restrict__ wgu,
    const int* __restrict__ cnt, const int* __restrict__ tok,
    unsigned short* __restrict__ act)
{
  const int e  = blockIdx.z;
  const int m0 = blockIdx.y * 128;
  const int f0 = blockIdx.x * 64;
  const int cn = cnt[e];
  if (m0 >= cn) return;
  int basev = 0;
#pragma unroll
  for (int i = 0; i < NE; ++i) { int ci = cnt[i]; if (i < e) basev += ci; }

  __shared__ uint4    As[1024];
  __shared__ uint32_t Bs[4096];

  const int tid  = threadIdx.x;
  const int lane = tid & 63;
  const int w    = tid >> 6;
  const int wm   = w >> 1, wn = w & 1;
  const int q    = lane >> 4;
  const int c    = lane & 15;

  floatx4 acc[4][4];
#pragma unroll
  for (int i = 0; i < 4; ++i)
#pragma unroll
    for (int j = 0; j < 4; ++j) acc[i][j] = (floatx4){0.f, 0.f, 0.f, 0.f};

  const float* wB  = wgu + (size_t)e * HIDDEN * (2 * FFN);
  const int* tokE  = tok + e * CAP;

  for (int kt = 0; kt < HIDDEN / 64; ++kt) {
    const int k0 = kt * 64;
    __syncthreads();
#pragma unroll
    for (int it = 0; it < 4; ++it) {
      int cid = it * 256 + tid;
      int row = cid >> 3, c8 = cid & 7;
      int mrow = m0 + row; if (mrow >= cn) mrow = cn - 1;
      int tk = tokE[mrow];
      As[row * 8 + (c8 ^ (row & 7))] = xb[(size_t)tk * (HIDDEN / 8) + (k0 >> 3) + c8];
    }
#pragma unroll
    for (int it = 0; it < 4; ++it) {
      int mid = it * 256 + tid;
      int kp = mid >> 5;
      int n  = (mid & 31) * 4;
      int col = f0 + ((n >> 6) << 5) + (n & 31) + (((n >> 5) & 1) ? FFN : 0);
      const float* src = wB + (size_t)(k0 + 2 * kp) * (2 * FFN) + col;
      float4 r0 = *(const float4*)src;
      float4 r1 = *(const float4*)(src + 2 * FFN);
      int widx = kp * 128 + (n ^ (((kp >> 2) & 1) << 4));
      *(uint4*)&Bs[widx] = make_uint4(pack2(r0.x, r1.x), pack2(r0.y, r1.y),
                                      pack2(r0.z, r1.z), pack2(r0.w, r1.w));
    }
    __syncthreads();
#pragma unroll
    for (int ks = 0; ks < 2; ++ks) {
      short8 af[4];
#pragma unroll
      for (int i = 0; i < 4; ++i) {
        int row = wm * 64 + i * 16 + c;
        int kc8 = ks * 4 + q;
        af[i] = as_short8(As[row * 8 + (kc8 ^ (row & 7))]);
      }
      short8 bfr[4];
#pragma unroll
      for (int j = 0; j < 4; ++j) {
        int n  = wn * 64 + j * 16 + c;
        int kp = ks * 16 + q * 4;
        int nn = n ^ ((q & 1) << 4);
        bfr[j] = as_short8(make_uint4(Bs[(kp + 0) * 128 + nn], Bs[(kp + 1) * 128 + nn],
                                      Bs[(kp + 2) * 128 + nn], Bs[(kp + 3) * 128 + nn]));
      }
#pragma unroll
      for (int i = 0; i < 4; ++i)
#pragma unroll
        for (int j = 0; j < 4; ++j)
          acc[i][j] = __builtin_amdgcn_mfma_f32_16x16x32_bf16(af[i], bfr[j], acc[i][j], 0, 0, 0);
    }
  }

#pragma unroll
  for (int i = 0; i < 4; ++i) {
#pragma unroll
    for (int r = 0; r < 4; ++r) {
      int m = m0 + wm * 64 + i * 16 + q * 4 + r;
      if (m < cn) {
#pragma unroll
        for (int j = 0; j < 2; ++j) {
          float g = acc[i][j][r];
          float u = acc[i][j + 2][r];
          float a = (g / (1.f + __expf(-g))) * u;
          act[(size_t)(basev + m) * FFN + (f0 + wn * 32 + j * 16 + c)] = (unsigned short)f2bf(a);
        }
      }
    }
  }
}

__global__ __launch_bounds__(256) void moe_down_lg(
    const uint4* __restrict__ actc, const float* __restrict__ wd,
    const int* __restrict__ cnt, const int* __restrict__ tok,
    const float* __restrict__ wgt, float* __restrict__ out)
{
  const int e  = blockIdx.z;
  const int m0 = blockIdx.y * 128;
  const int n0 = blockIdx.x * 128;
  const int cn = cnt[e];
  if (m0 >= cn) return;
  int basev = 0;
#pragma unroll
  for (int i = 0; i < NE; ++i) { int ci = cnt[i]; if (i < e) basev += ci; }

  __shared__ uint4    As[1024];
  __shared__ uint32_t Bs[4096];

  const int tid  = threadIdx.x;
  const int lane = tid & 63;
  const int w    = tid >> 6;
  const int wm   = w >> 1, wn = w & 1;
  const int q    = lane >> 4;
  const int c    = lane & 15;

  floatx4 acc[4][4];
#pragma unroll
  for (int i = 0; i < 4; ++i)
#pragma unroll
    for (int j = 0; j < 4; ++j) acc[i][j] = (floatx4){0.f, 0.f, 0.f, 0.f};

  const float* wB = wd + (size_t)e * FFN * HIDDEN;

  for (int kt = 0; kt < FFN / 64; ++kt) {
    const int k0 = kt * 64;
    __syncthreads();
#pragma unroll
    for (int it = 0; it < 4; ++it) {
      int cid = it * 256 + tid;
      int row = cid >> 3, c8 = cid & 7;
      int mrow = m0 + row; if (mrow >= cn) mrow = cn - 1;
      As[row * 8 + (c8 ^ (row & 7))] =
          actc[(size_t)(basev + mrow) * (FFN / 8) + (k0 >> 3) + c8];
    }
#pragma unroll
    for (int it = 0; it < 4; ++it) {
      int mid = it * 256 + tid;
      int kp = mid >> 5;
      int n  = (mid & 31) * 4;
      int col = n0 + n;
      const float* src = wB + (size_t)(k0 + 2 * kp) * HIDDEN + col;
      float4 r0 = *(const float4*)src;
      float4 r1 = *(const float4*)(src + HIDDEN);
      int widx = kp * 128 + (n ^ (((kp >> 2) & 1) << 4));
      *(uint4*)&Bs[widx] = make_uint4(pack2(r0.x, r1.x), pack2(r0.y, r1.y),
                                      pack2(r0.z, r1.z), pack2(r0.w, r1.w));
    }
    __syncthreads();
#pragma unroll
    for (int ks = 0; ks < 2; ++ks) {
      short8 af[4];
#pragma unroll
      for (int i = 0; i < 4; ++i) {
        int row = wm * 64 + i * 16 + c;
        int kc8 = ks * 4 + q;
        af[i] = as_short8(As[row * 8 + (kc8 ^ (row & 7))]);
      }
      short8 bfr[4];
#pragma unroll
      for (int j = 0; j < 4; ++j) {
        int n  = wn * 64 + j * 16 + c;
        int kp = ks * 16 + q * 4;
        int nn = n ^ ((q & 1) << 4);
        bfr[j] = as_short8(make_uint4(Bs[(kp + 0) * 128 + nn], Bs[(kp + 1) * 128 + nn],
                                      Bs[(kp + 2) * 128 + nn], Bs[(kp + 3) * 128 + nn]));
      }
#pragma unroll
      for (int i = 0; i < 4; ++i)
#pragma unroll
        for (int j = 0; j < 4; ++j)
          acc[i][j] = __builtin_amdgcn_mfma_f32_16x16x32_bf16(af[i], bfr[j], acc[i][j], 0, 0, 0);
    }
  }

#pragma unroll
  for (int i = 0; i < 4; ++i) {
#pragma unroll
    for (int r = 0; r < 4; ++r) {
      int m = m0 + wm * 64 + i * 16 + q * 4 + r;
      if (m < cn) {
        int   t  = tok[e * CAP + m];
        float wg = wgt[e * CAP + m];
        float* orow = out + (size_t)t * HIDDEN + n0 + wn * 64 + c;
#pragma unroll
        for (int j = 0; j < 4; ++j)
          atomicAdd(orow + j * 16, acc[i][j][r] * wg);
      }
    }
  }
}

extern "C" void kernel_launch(void* const* d_in, const int* in_sizes, int n_in,
                              void* d_out, int out_size, void* d_ws, size_t ws_size,
                              hipStream_t stream)
{
  (void)in_sizes; (void)n_in; (void)out_size;
  const float* x   = (const float*)d_in[0];
  const float* gw  = (const float*)d_in[1];
  const float* wgu = (const float*)d_in[2];
  const float* wd  = (const float*)d_in[3];
  float* out = (float*)d_out;
  char*  ws  = (char*)d_ws;

  uint4*          xb   = (uint4*)(ws + X_OFF);
  int*            cnt  = (int*)(ws + CNT_OFF);
  int*            tok  = (int*)(ws + TOK_OFF);
  float*          wgt  = (float*)(ws + WGT_OFF);
  int*            inv  = (int*)(ws + INV_OFF);
  unsigned short* act  = (unsigned short*)(ws + ACT_OFF);
  uint4*          wgub = (uint4*)(ws + WGU_OFF);
  uint4*          wdb  = (uint4*)(ws + WDB_OFF);
  float*          part = (float*)(ws + PART_OFF);

  const bool fast = (ws_size >= WS_NEED);

  if (fast) {
    moe_convert<<<(NTOK * HIDDEN) / (256 * 8), 256, 0, stream>>>((const float4*)x, xb, cnt);
    moe_router<<<NTOK / 4, 256, 0, stream>>>(x, gw, out + OUT_ELEMS, cnt, tok, wgt, inv);
    moe_wconv_gu<<<dim3(16, 56, NE), 256, 0, stream>>>(wgu, wgub);
    moe_wconv_d<<<dim3(56, 8, NE), 256, 0, stream>>>(wd, wdb);
    moe_gateup<<<dim3(FFN / 64, 16, NE), 256, 0, stream>>>(xb, wgub, cnt, tok, act);
    moe_down<<<dim3(HIDDEN / 128, 16, NE), 256, 0, stream>>>(act, wdb, cnt, tok, wgt, part);
    moe_combine<<<NTOK, 256, 0, stream>>>(cnt, inv, (const float4*)part, (float4*)out);
  } else {
    moe_prep<<<OUT_ELEMS / (256 * 4), 256, 0, stream>>>((float4*)out, cnt);
    moe_convert<<<(NTOK * HIDDEN) / (256 * 8), 256, 0, stream>>>((const float4*)x, xb, cnt);
    moe_router<<<NTOK / 4, 256, 0, stream>>>(x, gw, out + OUT_ELEMS, cnt, tok, wgt, inv);
    moe_gateup_lg<<<dim3(FFN / 64, 16, NE), 256, 0, stream>>>(xb, wgu, cnt, tok, act);
    moe_down_lg<<<dim3(HIDDEN / 128, 16, NE), 256, 0, stream>>>((const uint4*)act, wd, cnt, tok, wgt, out);
  }
}

// Round 4
// 664.451 us; speedup vs baseline: 1.0186x; 1.0186x over previous
//
#include <hip/hip_runtime.h>
#include <hip/hip_bf16.h>
#include <stdint.h>

#define HIDDEN  1024
#define FFN     3584
#define NE      8
#define NTOK    2048
#define CAP     2048
#define OUT_ELEMS (NTOK * HIDDEN)   /* 2097152 */

/* ---- workspace layout (bytes) ---- */
#define X_OFF    0u                          /* x as bf16: 2048*1024*2 = 4 MiB   */
#define CNT_OFF  (4u*1024u*1024u)            /* 8 int counters                   */
#define TOK_OFF  (CNT_OFF + 256u)            /* token lists: 8*2048*4 = 64 KiB   */
#define WGT_OFF  (TOK_OFF + 65536u)          /* combine weights: 64 KiB          */
#define INV_OFF  (WGT_OFF + 65536u)          /* token -> 2 slot ids: 16 KiB      */
#define ACT_OFF  (INV_OFF + 16384u)          /* packed act bf16: 4096*3584*2     */
#define ACT_SZ   (4096u * 3584u * 2u)        /* 29360128                         */
#define WGU_OFF  (ACT_OFF + ACT_SZ)          /* bf16 tiled gate/up weights       */
#define WGU_SZ   (8u*56u*16u*16384u)         /* 117440512 (112 MiB)              */
#define WDB_OFF  (WGU_OFF + WGU_SZ)          /* bf16 tiled down weights          */
#define WDB_SZ   (8u*8u*56u*16384u)          /* 58720256 (56 MiB)                */
#define PART_OFF (WDB_OFF + WDB_SZ)          /* fp32 partial rows: 4096*1024*4   */
#define PART_SZ  (4096u*1024u*4u)            /* 16 MiB                           */
#define WS_NEED  ((size_t)PART_OFF + (size_t)PART_SZ)

typedef __attribute__((ext_vector_type(8))) short short8;
typedef __attribute__((ext_vector_type(4))) float floatx4;

static __device__ __forceinline__ uint32_t f2bf(float f) {
  union { float f; uint32_t u; } v; v.f = f;
  return (v.u + 0x7FFFu + ((v.u >> 16) & 1u)) >> 16;   /* RNE */
}
static __device__ __forceinline__ uint32_t pack2(float lo, float hi) {
  return f2bf(lo) | (f2bf(hi) << 16);
}
union S8U { uint4 u; short8 s; };
static __device__ __forceinline__ short8 as_short8(uint4 v) { S8U x; x.u = v; return x.s; }

/* async global -> LDS, 16B per lane; LDS dest is wave-uniform base + lane*16 */
static __device__ __forceinline__ void ld_g2l16(const void* g, void* l) {
  __builtin_amdgcn_global_load_lds(
      (const __attribute__((address_space(1))) void*)g,
      (__attribute__((address_space(3))) void*)l, 16, 0, 0);
}

/* stage one 16KB A-tile + 16KB B-tile into the given LDS buffers */
static __device__ __forceinline__ void stage_tile(
    const char* const* aptr, const char* bptr, size_t akt, size_t bkt,
    uint4* AsB, uint4* BsB, int w)
{
#pragma unroll
  for (int it = 0; it < 4; ++it)
    ld_g2l16(aptr[it] + akt, &AsB[(w * 4 + it) * 64]);
#pragma unroll
  for (int it = 0; it < 4; ++it)
    ld_g2l16(bptr + bkt + (size_t)it * 1024u, &BsB[(w * 4 + it) * 64]);
}

/* ---- zero output accumulation region + expert counters (fallback only) ---- */
__global__ __launch_bounds__(256) void moe_prep(float4* __restrict__ out4,
                                                int* __restrict__ cnt) {
  uint32_t i = blockIdx.x * 256u + threadIdx.x;
  out4[i] = make_float4(0.f, 0.f, 0.f, 0.f);
  if (blockIdx.x == 0 && threadIdx.x < NE) cnt[threadIdx.x] = 0;
}

/* ---- x fp32 -> bf16 (+ cnt zero for fast path) ---- */
__global__ __launch_bounds__(256) void moe_convert(const float4* __restrict__ x4,
                                                   uint4* __restrict__ xb,
                                                   int* __restrict__ cnt) {
  uint32_t g = blockIdx.x * 256u + threadIdx.x;
  float4 a = x4[2u*g], b = x4[2u*g + 1u];
  xb[g] = make_uint4(pack2(a.x, a.y), pack2(a.z, a.w),
                     pack2(b.x, b.y), pack2(b.z, b.w));
  if (blockIdx.x == 0 && threadIdx.x < NE) cnt[threadIdx.x] = 0;
}

/* ---- router: one wave per token ---- */
__global__ __launch_bounds__(256) void moe_router(
    const float* __restrict__ x, const float* __restrict__ gw,
    float* __restrict__ logits, int* __restrict__ cnt,
    int* __restrict__ tok, float* __restrict__ wgt, int* __restrict__ inv)
{
  const int t = blockIdx.x * 4 + (threadIdx.x >> 6);
  const int lane = threadIdx.x & 63;
  const float* xr = x + (size_t)t * HIDDEN;
  float a[NE];
#pragma unroll
  for (int e = 0; e < NE; ++e) a[e] = 0.f;
  for (int hh = 0; hh < HIDDEN / 64; ++hh) {
    float xv = xr[hh * 64 + lane];
#pragma unroll
    for (int e = 0; e < NE; ++e) a[e] += xv * gw[e * HIDDEN + hh * 64 + lane];
  }
#pragma unroll
  for (int off = 32; off > 0; off >>= 1) {
#pragma unroll
    for (int e = 0; e < NE; ++e) a[e] += __shfl_xor(a[e], off);
  }
  if (lane == 0) {
#pragma unroll
    for (int e = 0; e < NE; ++e) logits[t * NE + e] = a[e];
    int i0 = 0; float v0 = a[0];
#pragma unroll
    for (int e = 1; e < NE; ++e) if (a[e] > v0) { v0 = a[e]; i0 = e; }
    int i1 = (i0 == 0) ? 1 : 0; float v1 = a[i1];
#pragma unroll
    for (int e = 0; e < NE; ++e) if (e != i0 && a[e] > v1) { v1 = a[e]; i1 = e; }
    float w0 = 1.f / (1.f + __expf(v1 - v0));
    float w1 = 1.f - w0;
    int p0 = atomicAdd(&cnt[i0], 1); tok[i0 * CAP + p0] = t; wgt[i0 * CAP + p0] = w0;
    int p1 = atomicAdd(&cnt[i1], 1); tok[i1 * CAP + p1] = t; wgt[i1 * CAP + p1] = w1;
    inv[t * 2 + 0] = i0 * CAP + p0;
    inv[t * 2 + 1] = i1 * CAP + p1;
  }
}

/* ==== weight preconvert: fp32 -> bf16, col-major chunked tile layout ====
 * Tile per (e, fb/nb, kt): 128 logical cols x 64 k, bf16.
 * Chunk (n, c8) = 8 k-consecutive bf16 of col(n), stored as uint4 at
 * [n*8 + (c8 ^ (n&7))] -- EXACTLY the A-tile image format, so the GEMM
 * B-fragment read is a single swizzled ds_read_b128 like A.            */
__global__ __launch_bounds__(256) void moe_wconv_gu(const float* __restrict__ wgu,
                                                    uint4* __restrict__ wgub) {
  const int kt = blockIdx.x, fb = blockIdx.y, e = blockIdx.z;
  const int f0 = fb * 64, k0 = kt * 64;
  const float* wB = wgu + (size_t)e * HIDDEN * (2 * FFN);
  uint4* dst = wgub + ((size_t)(e * 56 + fb) * 16 + kt) * 1024;

  __shared__ float lds_f[64 * 129];   /* [k][n], stride 129 (pack-read conflict-free) */

  /* load 64 rows x 128 logical cols, coalesced */
#pragma unroll
  for (int p = 0; p < 8; ++p) {
    int idx = p * 256 + threadIdx.x;        /* 0..2047 float4s */
    int r   = idx >> 5;                     /* k row 0..63     */
    int lc  = (idx & 31) * 4;               /* logical col     */
    int col = f0 + ((lc >> 6) << 5) + (lc & 31) + (((lc >> 5) & 1) ? FFN : 0);
    float4 v = *(const float4*)(wB + (size_t)(k0 + r) * (2 * FFN) + col);
    float* d = &lds_f[r * 129 + lc];
    d[0] = v.x; d[1] = v.y; d[2] = v.z; d[3] = v.w;
  }
  __syncthreads();
  /* pack: 1024 chunks */
#pragma unroll
  for (int p = 0; p < 4; ++p) {
    int m  = p * 256 + threadIdx.x;         /* 0..1023 */
    int ne = m >> 3, c8 = m & 7;
    float f[8];
#pragma unroll
    for (int kk = 0; kk < 8; ++kk) f[kk] = lds_f[(c8 * 8 + kk) * 129 + ne];
    dst[ne * 8 + (c8 ^ (ne & 7))] =
        make_uint4(pack2(f[0], f[1]), pack2(f[2], f[3]),
                   pack2(f[4], f[5]), pack2(f[6], f[7]));
  }
}

__global__ __launch_bounds__(256) void moe_wconv_d(const float* __restrict__ wd,
                                                   uint4* __restrict__ wdb) {
  const int kt = blockIdx.x, nb = blockIdx.y, e = blockIdx.z;
  const int n0 = nb * 128, k0 = kt * 64;
  const float* wB = wd + (size_t)e * FFN * HIDDEN;
  uint4* dst = wdb + ((size_t)(e * 8 + nb) * 56 + kt) * 1024;

  __shared__ float lds_f[64 * 129];

#pragma unroll
  for (int p = 0; p < 8; ++p) {
    int idx = p * 256 + threadIdx.x;
    int r   = idx >> 5;
    int lc  = (idx & 31) * 4;
    float4 v = *(const float4*)(wB + (size_t)(k0 + r) * HIDDEN + n0 + lc);
    float* d = &lds_f[r * 129 + lc];
    d[0] = v.x; d[1] = v.y; d[2] = v.z; d[3] = v.w;
  }
  __syncthreads();
#pragma unroll
  for (int p = 0; p < 4; ++p) {
    int m  = p * 256 + threadIdx.x;
    int ne = m >> 3, c8 = m & 7;
    float f[8];
#pragma unroll
    for (int kk = 0; kk < 8; ++kk) f[kk] = lds_f[(c8 * 8 + kk) * 129 + ne];
    dst[ne * 8 + (c8 ^ (ne & 7))] =
        make_uint4(pack2(f[0], f[1]), pack2(f[2], f[3]),
                   pack2(f[4], f[5]), pack2(f[6], f[7]));
  }
}

/* ==== grouped GEMM 1 (fast, 2-phase dbuf, b128 A+B frags) ==== */
__global__ __launch_bounds__(256) void moe_gateup(
    const uint4* __restrict__ xb, const uint4* __restrict__ wgub,
    const int* __restrict__ cnt, const int* __restrict__ tok,
    unsigned short* __restrict__ act)
{
  const int e  = blockIdx.z;
  const int m0 = blockIdx.y * 128;
  const int fb = blockIdx.x;
  const int f0 = fb * 64;
  const int cn = cnt[e];
  if (m0 >= cn) return;
  int basev = 0;
#pragma unroll
  for (int i = 0; i < NE; ++i) { int ci = cnt[i]; if (i < e) basev += ci; }

  __shared__ uint4 As[2][1024];
  __shared__ uint4 Bs4[2][1024];

  const int tid  = threadIdx.x;
  const int lane = tid & 63;
  const int w    = tid >> 6;
  const int wm   = w >> 1, wn = w & 1;
  const int q    = lane >> 4;
  const int c    = lane & 15;

  const int* tokE = tok + e * CAP;
  const char* aptr[4];
#pragma unroll
  for (int it = 0; it < 4; ++it) {
    int p   = (w * 4 + it) * 64 + lane;
    int row = p >> 3, c8 = p & 7;
    int mrow = m0 + row; if (mrow >= cn) mrow = cn - 1;
    aptr[it] = (const char*)(xb + (size_t)tokE[mrow] * (HIDDEN / 8) + (c8 ^ (row & 7)));
  }
  const char* bptr = (const char*)wgub + ((size_t)(e * 56 + fb) * 16) * 16384u
                   + (size_t)w * 4096u + (size_t)lane * 16u;

  floatx4 acc[4][4];
#pragma unroll
  for (int i = 0; i < 4; ++i)
#pragma unroll
    for (int j = 0; j < 4; ++j) acc[i][j] = (floatx4){0.f, 0.f, 0.f, 0.f};

  const int NT = HIDDEN / 64;
  stage_tile(aptr, bptr, 0, 0, As[0], Bs4[0], w);
  __syncthreads();
  int cur = 0;
  for (int kt = 0; kt < NT; ++kt) {
    if (kt + 1 < NT)
      stage_tile(aptr, bptr, (size_t)(kt + 1) * 128u, (size_t)(kt + 1) * 16384u,
                 As[cur ^ 1], Bs4[cur ^ 1], w);
    const uint4* Asc = As[cur];
    const uint4* Bsc = Bs4[cur];
#pragma unroll
    for (int ks = 0; ks < 2; ++ks) {
      const int kc8 = ks * 4 + q;
      short8 af[4];
#pragma unroll
      for (int i = 0; i < 4; ++i) {
        int row = wm * 64 + i * 16 + c;
        af[i] = as_short8(Asc[row * 8 + (kc8 ^ (row & 7))]);
      }
      short8 bfr[4];
#pragma unroll
      for (int j = 0; j < 4; ++j) {
        int n = wn * 64 + j * 16 + c;
        bfr[j] = as_short8(Bsc[n * 8 + (kc8 ^ (n & 7))]);
      }
#pragma unroll
      for (int i = 0; i < 4; ++i)
#pragma unroll
        for (int j = 0; j < 4; ++j)
          acc[i][j] = __builtin_amdgcn_mfma_f32_16x16x32_bf16(af[i], bfr[j], acc[i][j], 0, 0, 0);
    }
    __syncthreads();    /* drains prefetch DMA, releases both buffers */
    cur ^= 1;
  }

#pragma unroll
  for (int i = 0; i < 4; ++i) {
#pragma unroll
    for (int r = 0; r < 4; ++r) {
      int m = m0 + wm * 64 + i * 16 + q * 4 + r;
      if (m < cn) {
#pragma unroll
        for (int j = 0; j < 2; ++j) {
          float g = acc[i][j][r];
          float u = acc[i][j + 2][r];
          float a = (g / (1.f + __expf(-g))) * u;
          act[(size_t)(basev + m) * FFN + (f0 + wn * 32 + j * 16 + c)] = (unsigned short)f2bf(a);
        }
      }
    }
  }
}

/* ==== grouped GEMM 2 (fast, 2-phase dbuf, b128 A+B frags) ==== */
__global__ __launch_bounds__(256) void moe_down(
    const unsigned short* __restrict__ act, const uint4* __restrict__ wdb,
    const int* __restrict__ cnt, const int* __restrict__ tok,
    const float* __restrict__ wgt, float* __restrict__ part)
{
  const int e  = blockIdx.z;
  const int m0 = blockIdx.y * 128;
  const int nb = blockIdx.x;
  const int n0 = nb * 128;
  const int cn = cnt[e];
  if (m0 >= cn) return;
  int basev = 0;
#pragma unroll
  for (int i = 0; i < NE; ++i) { int ci = cnt[i]; if (i < e) basev += ci; }

  __shared__ uint4 As[2][1024];
  __shared__ uint4 Bs4[2][1024];

  const int tid  = threadIdx.x;
  const int lane = tid & 63;
  const int w    = tid >> 6;
  const int wm   = w >> 1, wn = w & 1;
  const int q    = lane >> 4;
  const int c    = lane & 15;

  const char* aptr[4];
#pragma unroll
  for (int it = 0; it < 4; ++it) {
    int p   = (w * 4 + it) * 64 + lane;
    int row = p >> 3, c8 = p & 7;
    int mrow = m0 + row; if (mrow >= cn) mrow = cn - 1;
    aptr[it] = (const char*)act +
               ((size_t)(basev + mrow) * FFN + (size_t)((c8 ^ (row & 7)) * 8)) * 2u;
  }
  const char* bptr = (const char*)wdb + ((size_t)(e * 8 + nb) * 56) * 16384u
                   + (size_t)w * 4096u + (size_t)lane * 16u;

  floatx4 acc[4][4];
#pragma unroll
  for (int i = 0; i < 4; ++i)
#pragma unroll
    for (int j = 0; j < 4; ++j) acc[i][j] = (floatx4){0.f, 0.f, 0.f, 0.f};

  const int NT = FFN / 64;
  stage_tile(aptr, bptr, 0, 0, As[0], Bs4[0], w);
  __syncthreads();
  int cur = 0;
  for (int kt = 0; kt < NT; ++kt) {
    if (kt + 1 < NT)
      stage_tile(aptr, bptr, (size_t)(kt + 1) * 128u, (size_t)(kt + 1) * 16384u,
                 As[cur ^ 1], Bs4[cur ^ 1], w);
    const uint4* Asc = As[cur];
    const uint4* Bsc = Bs4[cur];
#pragma unroll
    for (int ks = 0; ks < 2; ++ks) {
      const int kc8 = ks * 4 + q;
      short8 af[4];
#pragma unroll
      for (int i = 0; i < 4; ++i) {
        int row = wm * 64 + i * 16 + c;
        af[i] = as_short8(Asc[row * 8 + (kc8 ^ (row & 7))]);
      }
      short8 bfr[4];
#pragma unroll
      for (int j = 0; j < 4; ++j) {
        int n = wn * 64 + j * 16 + c;
        bfr[j] = as_short8(Bsc[n * 8 + (kc8 ^ (n & 7))]);
      }
#pragma unroll
      for (int i = 0; i < 4; ++i)
#pragma unroll
        for (int j = 0; j < 4; ++j)
          acc[i][j] = __builtin_amdgcn_mfma_f32_16x16x32_bf16(af[i], bfr[j], acc[i][j], 0, 0, 0);
    }
    __syncthreads();
    cur ^= 1;
  }

  /* epilogue: scale by combine weight, PLAIN store to packed partial row */
#pragma unroll
  for (int i = 0; i < 4; ++i) {
#pragma unroll
    for (int r = 0; r < 4; ++r) {
      int m = m0 + wm * 64 + i * 16 + q * 4 + r;
      if (m < cn) {
        float  wg   = wgt[e * CAP + m];
        float* prow = part + (size_t)(basev + m) * HIDDEN + n0 + wn * 64 + c;
#pragma unroll
        for (int j = 0; j < 4; ++j)
          prow[j * 16] = acc[i][j][r] * wg;
      }
    }
  }
}

/* ==== combine: out[t] = part[slot0(t)] + part[slot1(t)] ==== */
__global__ __launch_bounds__(256) void moe_combine(
    const int* __restrict__ cnt, const int* __restrict__ inv,
    const float4* __restrict__ part4, float4* __restrict__ out4)
{
  const int t  = blockIdx.x;
  const int s0 = inv[2 * t], s1 = inv[2 * t + 1];
  const int e0 = s0 >> 11, e1 = s1 >> 11;          /* CAP = 2048 */
  int b0 = 0, b1 = 0;
#pragma unroll
  for (int i = 0; i < NE; ++i) {
    int ci = cnt[i];
    if (i < e0) b0 += ci;
    if (i < e1) b1 += ci;
  }
  const size_t r0 = (size_t)(b0 + (s0 & (CAP - 1))) * 256u;
  const size_t r1 = (size_t)(b1 + (s1 & (CAP - 1))) * 256u;
  const int i = threadIdx.x;
  float4 a = part4[r0 + i];
  float4 b = part4[r1 + i];
  out4[(size_t)t * 256u + i] = make_float4(a.x + b.x, a.y + b.y, a.z + b.z, a.w + b.w);
}

/* ==== legacy fallback GEMMs (used only if workspace too small) ==== */
__global__ __launch_bounds__(256) void moe_gateup_lg(
    const uint4* __restrict__ xb, const float* __restrict__ wgu,
    const int* __restrict__ cnt, const int* __restrict__ tok,
    unsigned short* __restrict__ act)
{
  const int e  = blockIdx.z;
  const int m0 = blockIdx.y * 128;
  const int f0 = blockIdx.x * 64;
  const int cn = cnt[e];
  if (m0 >= cn) return;
  int basev = 0;
#pragma unroll
  for (int i = 0; i < NE; ++i) { int ci = cnt[i]; if (i < e) basev += ci; }

  __shared__ uint4    As[1024];
  __shared__ uint32_t Bs[4096];

  const int tid  = threadIdx.x;
  const int lane = tid & 63;
  const int w    = tid >> 6;
  const int wm   = w >> 1, wn = w & 1;
  const int q    = lane >> 4;
  const int c    = lane & 15;

  floatx4 acc[4][4];
#pragma unroll
  for (int i = 0; i < 4; ++i)
#pragma unroll
    for (int j = 0; j < 4; ++j) acc[i][j] = (floatx4){0.f, 0.f, 0.f, 0.f};

  const float* wB  = wgu + (size_t)e * HIDDEN * (2 * FFN);
  const int* tokE  = tok + e * CAP;

  for (int kt = 0; kt < HIDDEN / 64; ++kt) {
    const int k0 = kt * 64;
    __syncthreads();
#pragma unroll
    for (int it = 0; it < 4; ++it) {
      int cid = it * 256 + tid;
      int row = cid >> 3, c8 = cid & 7;
      int mrow = m0 + row; if (mrow >= cn) mrow = cn - 1;
      int tk = tokE[mrow];
      As[row * 8 + (c8 ^ (row & 7))] = xb[(size_t)tk * (HIDDEN / 8) + (k0 >> 3) + c8];
    }
#pragma unroll
    for (int it = 0; it < 4; ++it) {
      int mid = it * 256 + tid;
      int kp = mid >> 5;
      int n  = (mid & 31) * 4;
      int col = f0 + ((n >> 6) << 5) + (n & 31) + (((n >> 5) & 1) ? FFN : 0);
      const float* src = wB + (size_t)(k0 + 2 * kp) * (2 * FFN) + col;
      float4 r0 = *(const float4*)src;
      float4 r1 = *(const float4*)(src + 2 * FFN);
      int widx = kp * 128 + (n ^ (((kp >> 2) & 1) << 4));
      *(uint4*)&Bs[widx] = make_uint4(pack2(r0.x, r1.x), pack2(r0.y, r1.y),
                                      pack2(r0.z, r1.z), pack2(r0.w, r1.w));
    }
    __syncthreads();
#pragma unroll
    for (int ks = 0; ks < 2; ++ks) {
      short8 af[4];
#pragma unroll
      for (int i = 0; i < 4; ++i) {
        int row = wm * 64 + i * 16 + c;
        int kc8 = ks * 4 + q;
        af[i] = as_short8(As[row * 8 + (kc8 ^ (row & 7))]);
      }
      short8 bfr[4];
#pragma unroll
      for (int j = 0; j < 4; ++j) {
        int n  = wn * 64 + j * 16 + c;
        int kp = ks * 16 + q * 4;
        int nn = n ^ ((q & 1) << 4);
        bfr[j] = as_short8(make_uint4(Bs[(kp + 0) * 128 + nn], Bs[(kp + 1) * 128 + nn],
                                      Bs[(kp + 2) * 128 + nn], Bs[(kp + 3) * 128 + nn]));
      }
#pragma unroll
      for (int i = 0; i < 4; ++i)
#pragma unroll
        for (int j = 0; j < 4; ++j)
          acc[i][j] = __builtin_amdgcn_mfma_f32_16x16x32_bf16(af[i], bfr[j], acc[i][j], 0, 0, 0);
    }
  }

#pragma unroll
  for (int i = 0; i < 4; ++i) {
#pragma unroll
    for (int r = 0; r < 4; ++r) {
      int m = m0 + wm * 64 + i * 16 + q * 4 + r;
      if (m < cn) {
#pragma unroll
        for (int j = 0; j < 2; ++j) {
          float g = acc[i][j][r];
          float u = acc[i][j + 2][r];
          float a = (g / (1.f + __expf(-g))) * u;
          act[(size_t)(basev + m) * FFN + (f0 + wn * 32 + j * 16 + c)] = (unsigned short)f2bf(a);
        }
      }
    }
  }
}

__global__ __launch_bounds__(256) void moe_down_lg(
    const uint4* __restrict__ actc, const float* __restrict__ wd,
    const int* __restrict__ cnt, const int* __restrict__ tok,
    const float* __restrict__ wgt, float* __restrict__ out)
{
  const int e  = blockIdx.z;
  const int m0 = blockIdx.y * 128;
  const int n0 = blockIdx.x * 128;
  const int cn = cnt[e];
  if (m0 >= cn) return;
  int basev = 0;
#pragma unroll
  for (int i = 0; i < NE; ++i) { int ci = cnt[i]; if (i < e) basev += ci; }

  __shared__ uint4    As[1024];
  __shared__ uint32_t Bs[4096];

  const int tid  = threadIdx.x;
  const int lane = tid & 63;
  const int w    = tid >> 6;
  const int wm   = w >> 1, wn = w & 1;
  const int q    = lane >> 4;
  const int c    = lane & 15;

  floatx4 acc[4][4];
#pragma unroll
  for (int i = 0; i < 4; ++i)
#pragma unroll
    for (int j = 0; j < 4; ++j) acc[i][j] = (floatx4){0.f, 0.f, 0.f, 0.f};

  const float* wB = wd + (size_t)e * FFN * HIDDEN;

  for (int kt = 0; kt < FFN / 64; ++kt) {
    const int k0 = kt * 64;
    __syncthreads();
#pragma unroll
    for (int it = 0; it < 4; ++it) {
      int cid = it * 256 + tid;
      int row = cid >> 3, c8 = cid & 7;
      int mrow = m0 + row; if (mrow >= cn) mrow = cn - 1;
      As[row * 8 + (c8 ^ (row & 7))] =
          actc[(size_t)(basev + mrow) * (FFN / 8) + (k0 >> 3) + c8];
    }
#pragma unroll
    for (int it = 0; it < 4; ++it) {
      int mid = it * 256 + tid;
      int kp = mid >> 5;
      int n  = (mid & 31) * 4;
      int col = n0 + n;
      const float* src = wB + (size_t)(k0 + 2 * kp) * HIDDEN + col;
      float4 r0 = *(const float4*)src;
      float4 r1 = *(const float4*)(src + HIDDEN);
      int widx = kp * 128 + (n ^ (((kp >> 2) & 1) << 4));
      *(uint4*)&Bs[widx] = make_uint4(pack2(r0.x, r1.x), pack2(r0.y, r1.y),
                                      pack2(r0.z, r1.z), pack2(r0.w, r1.w));
    }
    __syncthreads();
#pragma unroll
    for (int ks = 0; ks < 2; ++ks) {
      short8 af[4];
#pragma unroll
      for (int i = 0; i < 4; ++i) {
        int row = wm * 64 + i * 16 + c;
        int kc8 = ks * 4 + q;
        af[i] = as_short8(As[row * 8 + (kc8 ^ (row & 7))]);
      }
      short8 bfr[4];
#pragma unroll
      for (int j = 0; j < 4; ++j) {
        int n  = wn * 64 + j * 16 + c;
        int kp = ks * 16 + q * 4;
        int nn = n ^ ((q & 1) << 4);
        bfr[j] = as_short8(make_uint4(Bs[(kp + 0) * 128 + nn], Bs[(kp + 1) * 128 + nn],
                                      Bs[(kp + 2) * 128 + nn], Bs[(kp + 3) * 128 + nn]));
      }
#pragma unroll
      for (int i = 0; i < 4; ++i)
#pragma unroll
        for (int j = 0; j < 4; ++j)
          acc[i][j] = __builtin_amdgcn_mfma_f32_16x16x32_bf16(af[i], bfr[j], acc[i][j], 0, 0, 0);
    }
  }

#pragma unroll
  for (int i = 0; i < 4; ++i) {
#pragma unroll
    for (int r = 0; r < 4; ++r) {
      int m = m0 + wm * 64 + i * 16 + q * 4 + r;
      if (m < cn) {
        int   t  = tok[e * CAP + m];
        float wg = wgt[e * CAP + m];
        float* orow = out + (size_t)t * HIDDEN + n0 + wn * 64 + c;
#pragma unroll
        for (int j = 0; j < 4; ++j)
          atomicAdd(orow + j * 16, acc[i][j][r] * wg);
      }
    }
  }
}

extern "C" void kernel_launch(void* const* d_in, const int* in_sizes, int n_in,
                              void* d_out, int out_size, void* d_ws, size_t ws_size,
                              hipStream_t stream)
{
  (void)in_sizes; (void)n_in; (void)out_size;
  const float* x   = (const float*)d_in[0];
  const float* gw  = (const float*)d_in[1];
  const float* wgu = (const float*)d_in[2];
  const float* wd  = (const float*)d_in[3];
  float* out = (float*)d_out;
  char*  ws  = (char*)d_ws;

  uint4*          xb   = (uint4*)(ws + X_OFF);
  int*            cnt  = (int*)(ws + CNT_OFF);
  int*            tok  = (int*)(ws + TOK_OFF);
  float*          wgt  = (float*)(ws + WGT_OFF);
  int*            inv  = (int*)(ws + INV_OFF);
  unsigned short* act  = (unsigned short*)(ws + ACT_OFF);
  uint4*          wgub = (uint4*)(ws + WGU_OFF);
  uint4*          wdb  = (uint4*)(ws + WDB_OFF);
  float*          part = (float*)(ws + PART_OFF);

  const bool fast = (ws_size >= WS_NEED);

  if (fast) {
    moe_convert<<<(NTOK * HIDDEN) / (256 * 8), 256, 0, stream>>>((const float4*)x, xb, cnt);
    moe_router<<<NTOK / 4, 256, 0, stream>>>(x, gw, out + OUT_ELEMS, cnt, tok, wgt, inv);
    moe_wconv_gu<<<dim3(16, 56, NE), 256, 0, stream>>>(wgu, wgub);
    moe_wconv_d<<<dim3(56, 8, NE), 256, 0, stream>>>(wd, wdb);
    moe_gateup<<<dim3(FFN / 64, 16, NE), 256, 0, stream>>>(xb, wgub, cnt, tok, act);
    moe_down<<<dim3(HIDDEN / 128, 16, NE), 256, 0, stream>>>(act, wdb, cnt, tok, wgt, part);
    moe_combine<<<NTOK, 256, 0, stream>>>(cnt, inv, (const float4*)part, (float4*)out);
  } else {
    moe_prep<<<OUT_ELEMS / (256 * 4), 256, 0, stream>>>((float4*)out, cnt);
    moe_convert<<<(NTOK * HIDDEN) / (256 * 8), 256, 0, stream>>>((const float4*)x, xb, cnt);
    moe_router<<<NTOK / 4, 256, 0, stream>>>(x, gw, out + OUT_ELEMS, cnt, tok, wgt, inv);
    moe_gateup_lg<<<dim3(FFN / 64, 16, NE), 256, 0, stream>>>(xb, wgu, cnt, tok, act);
    moe_down_lg<<<dim3(HIDDEN / 128, 16, NE), 256, 0, stream>>>((const uint4*)act, wd, cnt, tok, wgt, out);
  }
}

// Round 5
// 659.635 us; speedup vs baseline: 1.0260x; 1.0073x over previous
//
#include <hip/hip_runtime.h>
#include <hip/hip_bf16.h>
#include <stdint.h>

#define HIDDEN  1024
#define FFN     3584
#define NE      8
#define NTOK    2048
#define CAP     2048
#define OUT_ELEMS (NTOK * HIDDEN)   /* 2097152 */

/* ---- workspace layout (bytes) ---- */
#define X_OFF    0u                          /* x as bf16: 2048*1024*2 = 4 MiB   */
#define CNT_OFF  (4u*1024u*1024u)            /* 8 int counters                   */
#define TOK_OFF  (CNT_OFF + 256u)            /* token lists: 8*2048*4 = 64 KiB   */
#define WGT_OFF  (TOK_OFF + 65536u)          /* combine weights: 64 KiB          */
#define INV_OFF  (WGT_OFF + 65536u)          /* token -> 2 slot ids: 16 KiB      */
#define ACT_OFF  (INV_OFF + 16384u)          /* packed act bf16: 4096*3584*2     */
#define ACT_SZ   (4096u * 3584u * 2u)        /* 29360128                         */
#define WGU_OFF  (ACT_OFF + ACT_SZ)          /* bf16 tiled gate/up weights       */
#define WGU_SZ   (8u*56u*16u*16384u)         /* 117440512 (112 MiB)              */
#define WDB_OFF  (WGU_OFF + WGU_SZ)          /* bf16 tiled down weights          */
#define WDB_SZ   (8u*8u*56u*16384u)          /* 58720256 (56 MiB)                */
#define PART_OFF (WDB_OFF + WDB_SZ)          /* fp32 partial rows: 4096*1024*4   */
#define PART_SZ  (4096u*1024u*4u)            /* 16 MiB                           */
#define WS_NEED  ((size_t)PART_OFF + (size_t)PART_SZ)

typedef __attribute__((ext_vector_type(8))) short short8;
typedef __attribute__((ext_vector_type(4))) float floatx4;

static __device__ __forceinline__ uint32_t f2bf(float f) {
  union { float f; uint32_t u; } v; v.f = f;
  return (v.u + 0x7FFFu + ((v.u >> 16) & 1u)) >> 16;   /* RNE */
}
static __device__ __forceinline__ uint32_t pack2(float lo, float hi) {
  return f2bf(lo) | (f2bf(hi) << 16);
}
union S8U { uint4 u; short8 s; };
static __device__ __forceinline__ short8 as_short8(uint4 v) { S8U x; x.u = v; return x.s; }

/* async global -> LDS, 16B per lane; LDS dest is wave-uniform base + lane*16 */
static __device__ __forceinline__ void ld_g2l16(const void* g, void* l) {
  __builtin_amdgcn_global_load_lds(
      (const __attribute__((address_space(1))) void*)g,
      (__attribute__((address_space(3))) void*)l, 16, 0, 0);
}

/* stage one 16KB A-tile + 16KB B-tile into the given LDS buffers (8 vmem/wave) */
static __device__ __forceinline__ void stage_tile(
    const char* const* aptr, const char* bptr, size_t akt, size_t bkt,
    uint4* AsB, uint4* BsB, int w)
{
#pragma unroll
  for (int it = 0; it < 4; ++it)
    ld_g2l16(aptr[it] + akt, &AsB[(w * 4 + it) * 64]);
#pragma unroll
  for (int it = 0; it < 4; ++it)
    ld_g2l16(bptr + bkt + (size_t)it * 1024u, &BsB[(w * 4 + it) * 64]);
}

/* counted-vmcnt sync (T4): tile t's 8 loads done, tile t+1's 8 stay in flight */
#define WAIT_VM8()  do { __builtin_amdgcn_sched_barrier(0); \
                         asm volatile("s_waitcnt vmcnt(8)" ::: "memory"); } while (0)
#define WAIT_VM0()  do { __builtin_amdgcn_sched_barrier(0); \
                         asm volatile("s_waitcnt vmcnt(0)" ::: "memory"); } while (0)
#define BAR()       do { __builtin_amdgcn_s_barrier(); \
                         __builtin_amdgcn_sched_barrier(0); } while (0)
#define ENDBAR()    do { __builtin_amdgcn_sched_barrier(0); \
                         __builtin_amdgcn_s_barrier(); } while (0)

/* ---- zero output accumulation region + expert counters (fallback only) ---- */
__global__ __launch_bounds__(256) void moe_prep(float4* __restrict__ out4,
                                                int* __restrict__ cnt) {
  uint32_t i = blockIdx.x * 256u + threadIdx.x;
  out4[i] = make_float4(0.f, 0.f, 0.f, 0.f);
  if (blockIdx.x == 0 && threadIdx.x < NE) cnt[threadIdx.x] = 0;
}

/* ---- x fp32 -> bf16 (+ cnt zero for fast path) ---- */
__global__ __launch_bounds__(256) void moe_convert(const float4* __restrict__ x4,
                                                   uint4* __restrict__ xb,
                                                   int* __restrict__ cnt) {
  uint32_t g = blockIdx.x * 256u + threadIdx.x;
  float4 a = x4[2u*g], b = x4[2u*g + 1u];
  xb[g] = make_uint4(pack2(a.x, a.y), pack2(a.z, a.w),
                     pack2(b.x, b.y), pack2(b.z, b.w));
  if (blockIdx.x == 0 && threadIdx.x < NE) cnt[threadIdx.x] = 0;
}

/* ---- router: one wave per token ---- */
__global__ __launch_bounds__(256) void moe_router(
    const float* __restrict__ x, const float* __restrict__ gw,
    float* __restrict__ logits, int* __restrict__ cnt,
    int* __restrict__ tok, float* __restrict__ wgt, int* __restrict__ inv)
{
  const int t = blockIdx.x * 4 + (threadIdx.x >> 6);
  const int lane = threadIdx.x & 63;
  const float* xr = x + (size_t)t * HIDDEN;
  float a[NE];
#pragma unroll
  for (int e = 0; e < NE; ++e) a[e] = 0.f;
  for (int hh = 0; hh < HIDDEN / 64; ++hh) {
    float xv = xr[hh * 64 + lane];
#pragma unroll
    for (int e = 0; e < NE; ++e) a[e] += xv * gw[e * HIDDEN + hh * 64 + lane];
  }
#pragma unroll
  for (int off = 32; off > 0; off >>= 1) {
#pragma unroll
    for (int e = 0; e < NE; ++e) a[e] += __shfl_xor(a[e], off);
  }
  if (lane == 0) {
#pragma unroll
    for (int e = 0; e < NE; ++e) logits[t * NE + e] = a[e];
    int i0 = 0; float v0 = a[0];
#pragma unroll
    for (int e = 1; e < NE; ++e) if (a[e] > v0) { v0 = a[e]; i0 = e; }
    int i1 = (i0 == 0) ? 1 : 0; float v1 = a[i1];
#pragma unroll
    for (int e = 0; e < NE; ++e) if (e != i0 && a[e] > v1) { v1 = a[e]; i1 = e; }
    float w0 = 1.f / (1.f + __expf(v1 - v0));
    float w1 = 1.f - w0;
    int p0 = atomicAdd(&cnt[i0], 1); tok[i0 * CAP + p0] = t; wgt[i0 * CAP + p0] = w0;
    int p1 = atomicAdd(&cnt[i1], 1); tok[i1 * CAP + p1] = t; wgt[i1 * CAP + p1] = w1;
    inv[t * 2 + 0] = i0 * CAP + p0;
    inv[t * 2 + 1] = i1 * CAP + p1;
  }
}

/* ==== weight preconvert: fp32 -> bf16, col-major chunked tile layout ====
 * Tile per (e, fb/nb, kt): 128 logical cols x 64 k, bf16.
 * Chunk (n, c8) = 8 k-consecutive bf16 of col(n), stored as uint4 at
 * [n*8 + (c8 ^ (n&7))] -- EXACTLY the A-tile image format, so the GEMM
 * B-fragment read is a single swizzled ds_read_b128 like A.            */
__global__ __launch_bounds__(256) void moe_wconv_gu(const float* __restrict__ wgu,
                                                    uint4* __restrict__ wgub) {
  const int kt = blockIdx.x, fb = blockIdx.y, e = blockIdx.z;
  const int f0 = fb * 64, k0 = kt * 64;
  const float* wB = wgu + (size_t)e * HIDDEN * (2 * FFN);
  uint4* dst = wgub + ((size_t)(e * 56 + fb) * 16 + kt) * 1024;

  __shared__ float lds_f[64 * 129];   /* [k][n], stride 129 (pack-read conflict-free) */

#pragma unroll
  for (int p = 0; p < 8; ++p) {
    int idx = p * 256 + threadIdx.x;        /* 0..2047 float4s */
    int r   = idx >> 5;                     /* k row 0..63     */
    int lc  = (idx & 31) * 4;               /* logical col     */
    int col = f0 + ((lc >> 6) << 5) + (lc & 31) + (((lc >> 5) & 1) ? FFN : 0);
    float4 v = *(const float4*)(wB + (size_t)(k0 + r) * (2 * FFN) + col);
    float* d = &lds_f[r * 129 + lc];
    d[0] = v.x; d[1] = v.y; d[2] = v.z; d[3] = v.w;
  }
  __syncthreads();
#pragma unroll
  for (int p = 0; p < 4; ++p) {
    int m  = p * 256 + threadIdx.x;         /* 0..1023 */
    int ne = m >> 3, c8 = m & 7;
    float f[8];
#pragma unroll
    for (int kk = 0; kk < 8; ++kk) f[kk] = lds_f[(c8 * 8 + kk) * 129 + ne];
    dst[ne * 8 + (c8 ^ (ne & 7))] =
        make_uint4(pack2(f[0], f[1]), pack2(f[2], f[3]),
                   pack2(f[4], f[5]), pack2(f[6], f[7]));
  }
}

__global__ __launch_bounds__(256) void moe_wconv_d(const float* __restrict__ wd,
                                                   uint4* __restrict__ wdb) {
  const int kt = blockIdx.x, nb = blockIdx.y, e = blockIdx.z;
  const int n0 = nb * 128, k0 = kt * 64;
  const float* wB = wd + (size_t)e * FFN * HIDDEN;
  uint4* dst = wdb + ((size_t)(e * 8 + nb) * 56 + kt) * 1024;

  __shared__ float lds_f[64 * 129];

#pragma unroll
  for (int p = 0; p < 8; ++p) {
    int idx = p * 256 + threadIdx.x;
    int r   = idx >> 5;
    int lc  = (idx & 31) * 4;
    float4 v = *(const float4*)(wB + (size_t)(k0 + r) * HIDDEN + n0 + lc);
    float* d = &lds_f[r * 129 + lc];
    d[0] = v.x; d[1] = v.y; d[2] = v.z; d[3] = v.w;
  }
  __syncthreads();
#pragma unroll
  for (int p = 0; p < 4; ++p) {
    int m  = p * 256 + threadIdx.x;
    int ne = m >> 3, c8 = m & 7;
    float f[8];
#pragma unroll
    for (int kk = 0; kk < 8; ++kk) f[kk] = lds_f[(c8 * 8 + kk) * 129 + ne];
    dst[ne * 8 + (c8 ^ (ne & 7))] =
        make_uint4(pack2(f[0], f[1]), pack2(f[2], f[3]),
                   pack2(f[4], f[5]), pack2(f[6], f[7]));
  }
}

/* ==== grouped GEMM 1 (fast, dbuf + counted-vmcnt pipeline) ==== */
__global__ __launch_bounds__(256) void moe_gateup(
    const uint4* __restrict__ xb, const uint4* __restrict__ wgub,
    const int* __restrict__ cnt, const int* __restrict__ tok,
    unsigned short* __restrict__ act)
{
  const int e  = blockIdx.z;
  const int m0 = blockIdx.y * 128;
  const int fb = blockIdx.x;
  const int f0 = fb * 64;
  const int cn = cnt[e];
  if (m0 >= cn) return;
  int basev = 0;
#pragma unroll
  for (int i = 0; i < NE; ++i) { int ci = cnt[i]; if (i < e) basev += ci; }

  __shared__ uint4 As[2][1024];
  __shared__ uint4 Bs4[2][1024];

  const int tid  = threadIdx.x;
  const int lane = tid & 63;
  const int w    = tid >> 6;
  const int wm   = w >> 1, wn = w & 1;
  const int q    = lane >> 4;
  const int c    = lane & 15;

  const int* tokE = tok + e * CAP;
  const char* aptr[4];
#pragma unroll
  for (int it = 0; it < 4; ++it) {
    int p   = (w * 4 + it) * 64 + lane;
    int row = p >> 3, c8 = p & 7;
    int mrow = m0 + row; if (mrow >= cn) mrow = cn - 1;
    aptr[it] = (const char*)(xb + (size_t)tokE[mrow] * (HIDDEN / 8) + (c8 ^ (row & 7)));
  }
  const char* bptr = (const char*)wgub + ((size_t)(e * 56 + fb) * 16) * 16384u
                   + (size_t)w * 4096u + (size_t)lane * 16u;

  floatx4 acc[4][4];
#pragma unroll
  for (int i = 0; i < 4; ++i)
#pragma unroll
    for (int j = 0; j < 4; ++j) acc[i][j] = (floatx4){0.f, 0.f, 0.f, 0.f};

  const int NT = HIDDEN / 64;
  stage_tile(aptr, bptr, 0, 0, As[0], Bs4[0], w);
  int cur = 0;
  for (int kt = 0; kt < NT; ++kt) {
    if (kt + 1 < NT) {
      stage_tile(aptr, bptr, (size_t)(kt + 1) * 128u, (size_t)(kt + 1) * 16384u,
                 As[cur ^ 1], Bs4[cur ^ 1], w);
      WAIT_VM8();             /* tile kt landed; kt+1's 8 loads stay in flight */
    } else {
      WAIT_VM0();
    }
    BAR();
    const uint4* Asc = As[cur];
    const uint4* Bsc = Bs4[cur];
#pragma unroll
    for (int ks = 0; ks < 2; ++ks) {
      const int kc8 = ks * 4 + q;
      short8 af[4];
#pragma unroll
      for (int i = 0; i < 4; ++i) {
        int row = wm * 64 + i * 16 + c;
        af[i] = as_short8(Asc[row * 8 + (kc8 ^ (row & 7))]);
      }
      short8 bfr[4];
#pragma unroll
      for (int j = 0; j < 4; ++j) {
        int n = wn * 64 + j * 16 + c;
        bfr[j] = as_short8(Bsc[n * 8 + (kc8 ^ (n & 7))]);
      }
#pragma unroll
      for (int i = 0; i < 4; ++i)
#pragma unroll
        for (int j = 0; j < 4; ++j)
          acc[i][j] = __builtin_amdgcn_mfma_f32_16x16x32_bf16(af[i], bfr[j], acc[i][j], 0, 0, 0);
    }
    ENDBAR();                 /* all waves done reading buf[cur] before kt+2 overwrites */
    cur ^= 1;
  }

#pragma unroll
  for (int i = 0; i < 4; ++i) {
#pragma unroll
    for (int r = 0; r < 4; ++r) {
      int m = m0 + wm * 64 + i * 16 + q * 4 + r;
      if (m < cn) {
#pragma unroll
        for (int j = 0; j < 2; ++j) {
          float g = acc[i][j][r];
          float u = acc[i][j + 2][r];
          float a = (g / (1.f + __expf(-g))) * u;
          act[(size_t)(basev + m) * FFN + (f0 + wn * 32 + j * 16 + c)] = (unsigned short)f2bf(a);
        }
      }
    }
  }
}

/* ==== grouped GEMM 2 (fast, dbuf + counted-vmcnt pipeline) ==== */
__global__ __launch_bounds__(256) void moe_down(
    const unsigned short* __restrict__ act, const uint4* __restrict__ wdb,
    const int* __restrict__ cnt, const int* __restrict__ tok,
    const float* __restrict__ wgt, float* __restrict__ part)
{
  const int e  = blockIdx.z;
  const int m0 = blockIdx.y * 128;
  const int nb = blockIdx.x;
  const int n0 = nb * 128;
  const int cn = cnt[e];
  if (m0 >= cn) return;
  int basev = 0;
#pragma unroll
  for (int i = 0; i < NE; ++i) { int ci = cnt[i]; if (i < e) basev += ci; }

  __shared__ uint4 As[2][1024];
  __shared__ uint4 Bs4[2][1024];

  const int tid  = threadIdx.x;
  const int lane = tid & 63;
  const int w    = tid >> 6;
  const int wm   = w >> 1, wn = w & 1;
  const int q    = lane >> 4;
  const int c    = lane & 15;

  const char* aptr[4];
#pragma unroll
  for (int it = 0; it < 4; ++it) {
    int p   = (w * 4 + it) * 64 + lane;
    int row = p >> 3, c8 = p & 7;
    int mrow = m0 + row; if (mrow >= cn) mrow = cn - 1;
    aptr[it] = (const char*)act +
               ((size_t)(basev + mrow) * FFN + (size_t)((c8 ^ (row & 7)) * 8)) * 2u;
  }
  const char* bptr = (const char*)wdb + ((size_t)(e * 8 + nb) * 56) * 16384u
                   + (size_t)w * 4096u + (size_t)lane * 16u;

  floatx4 acc[4][4];
#pragma unroll
  for (int i = 0; i < 4; ++i)
#pragma unroll
    for (int j = 0; j < 4; ++j) acc[i][j] = (floatx4){0.f, 0.f, 0.f, 0.f};

  const int NT = FFN / 64;
  stage_tile(aptr, bptr, 0, 0, As[0], Bs4[0], w);
  int cur = 0;
  for (int kt = 0; kt < NT; ++kt) {
    if (kt + 1 < NT) {
      stage_tile(aptr, bptr, (size_t)(kt + 1) * 128u, (size_t)(kt + 1) * 16384u,
                 As[cur ^ 1], Bs4[cur ^ 1], w);
      WAIT_VM8();
    } else {
      WAIT_VM0();
    }
    BAR();
    const uint4* Asc = As[cur];
    const uint4* Bsc = Bs4[cur];
#pragma unroll
    for (int ks = 0; ks < 2; ++ks) {
      const int kc8 = ks * 4 + q;
      short8 af[4];
#pragma unroll
      for (int i = 0; i < 4; ++i) {
        int row = wm * 64 + i * 16 + c;
        af[i] = as_short8(Asc[row * 8 + (kc8 ^ (row & 7))]);
      }
      short8 bfr[4];
#pragma unroll
      for (int j = 0; j < 4; ++j) {
        int n = wn * 64 + j * 16 + c;
        bfr[j] = as_short8(Bsc[n * 8 + (kc8 ^ (n & 7))]);
      }
#pragma unroll
      for (int i = 0; i < 4; ++i)
#pragma unroll
        for (int j = 0; j < 4; ++j)
          acc[i][j] = __builtin_amdgcn_mfma_f32_16x16x32_bf16(af[i], bfr[j], acc[i][j], 0, 0, 0);
    }
    ENDBAR();
    cur ^= 1;
  }

  /* epilogue: scale by combine weight, PLAIN store to packed partial row */
#pragma unroll
  for (int i = 0; i < 4; ++i) {
#pragma unroll
    for (int r = 0; r < 4; ++r) {
      int m = m0 + wm * 64 + i * 16 + q * 4 + r;
      if (m < cn) {
        float  wg   = wgt[e * CAP + m];
        float* prow = part + (size_t)(basev + m) * HIDDEN + n0 + wn * 64 + c;
#pragma unroll
        for (int j = 0; j < 4; ++j)
          prow[j * 16] = acc[i][j][r] * wg;
      }
    }
  }
}

/* ==== combine: out[t] = part[slot0(t)] + part[slot1(t)] ==== */
__global__ __launch_bounds__(256) void moe_combine(
    const int* __restrict__ cnt, const int* __restrict__ inv,
    const float4* __restrict__ part4, float4* __restrict__ out4)
{
  const int t  = blockIdx.x;
  const int s0 = inv[2 * t], s1 = inv[2 * t + 1];
  const int e0 = s0 >> 11, e1 = s1 >> 11;          /* CAP = 2048 */
  int b0 = 0, b1 = 0;
#pragma unroll
  for (int i = 0; i < NE; ++i) {
    int ci = cnt[i];
    if (i < e0) b0 += ci;
    if (i < e1) b1 += ci;
  }
  const size_t r0 = (size_t)(b0 + (s0 & (CAP - 1))) * 256u;
  const size_t r1 = (size_t)(b1 + (s1 & (CAP - 1))) * 256u;
  const int i = threadIdx.x;
  float4 a = part4[r0 + i];
  float4 b = part4[r1 + i];
  out4[(size_t)t * 256u + i] = make_float4(a.x + b.x, a.y + b.y, a.z + b.z, a.w + b.w);
}

/* ==== legacy fallback GEMMs (used only if workspace too small) ==== */
__global__ __launch_bounds__(256) void moe_gateup_lg(
    const uint4* __restrict__ xb, const float* __restrict__ wgu,
    const int* __restrict__ cnt, const int* __restrict__ tok,
    unsigned short* __restrict__ act)
{
  const int e  = blockIdx.z;
  const int m0 = blockIdx.y * 128;
  const int f0 = blockIdx.x * 64;
  const int cn = cnt[e];
  if (m0 >= cn) return;
  int basev = 0;
#pragma unroll
  for (int i = 0; i < NE; ++i) { int ci = cnt[i]; if (i < e) basev += ci; }

  __shared__ uint4    As[1024];
  __shared__ uint32_t Bs[4096];

  const int tid  = threadIdx.x;
  const int lane = tid & 63;
  const int w    = tid >> 6;
  const int wm   = w >> 1, wn = w & 1;
  const int q    = lane >> 4;
  const int c    = lane & 15;

  floatx4 acc[4][4];
#pragma unroll
  for (int i = 0; i < 4; ++i)
#pragma unroll
    for (int j = 0; j < 4; ++j) acc[i][j] = (floatx4){0.f, 0.f, 0.f, 0.f};

  const float* wB  = wgu + (size_t)e * HIDDEN * (2 * FFN);
  const int* tokE  = tok + e * CAP;

  for (int kt = 0; kt < HIDDEN / 64; ++kt) {
    const int k0 = kt * 64;
    __syncthreads();
#pragma unroll
    for (int it = 0; it < 4; ++it) {
      int cid = it * 256 + tid;
      int row = cid >> 3, c8 = cid & 7;
      int mrow = m0 + row; if (mrow >= cn) mrow = cn - 1;
      int tk = tokE[mrow];
      As[row * 8 + (c8 ^ (row & 7))] = xb[(size_t)tk * (HIDDEN / 8) + (k0 >> 3) + c8];
    }
#pragma unroll
    for (int it = 0; it < 4; ++it) {
      int mid = it * 256 + tid;
      int kp = mid >> 5;
      int n  = (mid & 31) * 4;
      int col = f0 + ((n >> 6) << 5) + (n & 31) + (((n >> 5) & 1) ? FFN : 0);
      const float* src = wB + (size_t)(k0 + 2 * kp) * (2 * FFN) + col;
      float4 r0 = *(const float4*)src;
      float4 r1 = *(const float4*)(src + 2 * FFN);
      int widx = kp * 128 + (n ^ (((kp >> 2) & 1) << 4));
      *(uint4*)&Bs[widx] = make_uint4(pack2(r0.x, r1.x), pack2(r0.y, r1.y),
                                      pack2(r0.z, r1.z), pack2(r0.w, r1.w));
    }
    __syncthreads();
#pragma unroll
    for (int ks = 0; ks < 2; ++ks) {
      short8 af[4];
#pragma unroll
      for (int i = 0; i < 4; ++i) {
        int row = wm * 64 + i * 16 + c;
        int kc8 = ks * 4 + q;
        af[i] = as_short8(As[row * 8 + (kc8 ^ (row & 7))]);
      }
      short8 bfr[4];
#pragma unroll
      for (int j = 0; j < 4; ++j) {
        int n  = wn * 64 + j * 16 + c;
        int kp = ks * 16 + q * 4;
        int nn = n ^ ((q & 1) << 4);
        bfr[j] = as_short8(make_uint4(Bs[(kp + 0) * 128 + nn], Bs[(kp + 1) * 128 + nn],
                                      Bs[(kp + 2) * 128 + nn], Bs[(kp + 3) * 128 + nn]));
      }
#pragma unroll
      for (int i = 0; i < 4; ++i)
#pragma unroll
        for (int j = 0; j < 4; ++j)
          acc[i][j] = __builtin_amdgcn_mfma_f32_16x16x32_bf16(af[i], bfr[j], acc[i][j], 0, 0, 0);
    }
  }

#pragma unroll
  for (int i = 0; i < 4; ++i) {
#pragma unroll
    for (int r = 0; r < 4; ++r) {
      int m = m0 + wm * 64 + i * 16 + q * 4 + r;
      if (m < cn) {
#pragma unroll
        for (int j = 0; j < 2; ++j) {
          float g = acc[i][j][r];
          float u = acc[i][j + 2][r];
          float a = (g / (1.f + __expf(-g))) * u;
          act[(size_t)(basev + m) * FFN + (f0 + wn * 32 + j * 16 + c)] = (unsigned short)f2bf(a);
        }
      }
    }
  }
}

__global__ __launch_bounds__(256) void moe_down_lg(
    const uint4* __restrict__ actc, const float* __restrict__ wd,
    const int* __restrict__ cnt, const int* __restrict__ tok,
    const float* __restrict__ wgt, float* __restrict__ out)
{
  const int e  = blockIdx.z;
  const int m0 = blockIdx.y * 128;
  const int n0 = blockIdx.x * 128;
  const int cn = cnt[e];
  if (m0 >= cn) return;
  int basev = 0;
#pragma unroll
  for (int i = 0; i < NE; ++i) { int ci = cnt[i]; if (i < e) basev += ci; }

  __shared__ uint4    As[1024];
  __shared__ uint32_t Bs[4096];

  const int tid  = threadIdx.x;
  const int lane = tid & 63;
  const int w    = tid >> 6;
  const int wm   = w >> 1, wn = w & 1;
  const int q    = lane >> 4;
  const int c    = lane & 15;

  floatx4 acc[4][4];
#pragma unroll
  for (int i = 0; i < 4; ++i)
#pragma unroll
    for (int j = 0; j < 4; ++j) acc[i][j] = (floatx4){0.f, 0.f, 0.f, 0.f};

  const float* wB = wd + (size_t)e * FFN * HIDDEN;

  for (int kt = 0; kt < FFN / 64; ++kt) {
    const int k0 = kt * 64;
    __syncthreads();
#pragma unroll
    for (int it = 0; it < 4; ++it) {
      int cid = it * 256 + tid;
      int row = cid >> 3, c8 = cid & 7;
      int mrow = m0 + row; if (mrow >= cn) mrow = cn - 1;
      As[row * 8 + (c8 ^ (row & 7))] =
          actc[(size_t)(basev + mrow) * (FFN / 8) + (k0 >> 3) + c8];
    }
#pragma unroll
    for (int it = 0; it < 4; ++it) {
      int mid = it * 256 + tid;
      int kp = mid >> 5;
      int n  = (mid & 31) * 4;
      int col = n0 + n;
      const float* src = wB + (size_t)(k0 + 2 * kp) * HIDDEN + col;
      float4 r0 = *(const float4*)src;
      float4 r1 = *(const float4*)(src + HIDDEN);
      int widx = kp * 128 + (n ^ (((kp >> 2) & 1) << 4));
      *(uint4*)&Bs[widx] = make_uint4(pack2(r0.x, r1.x), pack2(r0.y, r1.y),
                                      pack2(r0.z, r1.z), pack2(r0.w, r1.w));
    }
    __syncthreads();
#pragma unroll
    for (int ks = 0; ks < 2; ++ks) {
      short8 af[4];
#pragma unroll
      for (int i = 0; i < 4; ++i) {
        int row = wm * 64 + i * 16 + c;
        int kc8 = ks * 4 + q;
        af[i] = as_short8(As[row * 8 + (kc8 ^ (row & 7))]);
      }
      short8 bfr[4];
#pragma unroll
      for (int j = 0; j < 4; ++j) {
        int n  = wn * 64 + j * 16 + c;
        int kp = ks * 16 + q * 4;
        int nn = n ^ ((q & 1) << 4);
        bfr[j] = as_short8(make_uint4(Bs[(kp + 0) * 128 + nn], Bs[(kp + 1) * 128 + nn],
                                      Bs[(kp + 2) * 128 + nn], Bs[(kp + 3) * 128 + nn]));
      }
#pragma unroll
      for (int i = 0; i < 4; ++i)
#pragma unroll
        for (int j = 0; j < 4; ++j)
          acc[i][j] = __builtin_amdgcn_mfma_f32_16x16x32_bf16(af[i], bfr[j], acc[i][j], 0, 0, 0);
    }
  }

#pragma unroll
  for (int i = 0; i < 4; ++i) {
#pragma unroll
    for (int r = 0; r < 4; ++r) {
      int m = m0 + wm * 64 + i * 16 + q * 4 + r;
      if (m < cn) {
        int   t  = tok[e * CAP + m];
        float wg = wgt[e * CAP + m];
        float* orow = out + (size_t)t * HIDDEN + n0 + wn * 64 + c;
#pragma unroll
        for (int j = 0; j < 4; ++j)
          atomicAdd(orow + j * 16, acc[i][j][r] * wg);
      }
    }
  }
}

extern "C" void kernel_launch(void* const* d_in, const int* in_sizes, int n_in,
                              void* d_out, int out_size, void* d_ws, size_t ws_size,
                              hipStream_t stream)
{
  (void)in_sizes; (void)n_in; (void)out_size;
  const float* x   = (const float*)d_in[0];
  const float* gw  = (const float*)d_in[1];
  const float* wgu = (const float*)d_in[2];
  const float* wd  = (const float*)d_in[3];
  float* out = (float*)d_out;
  char*  ws  = (char*)d_ws;

  uint4*          xb   = (uint4*)(ws + X_OFF);
  int*            cnt  = (int*)(ws + CNT_OFF);
  int*            tok  = (int*)(ws + TOK_OFF);
  float*          wgt  = (float*)(ws + WGT_OFF);
  int*            inv  = (int*)(ws + INV_OFF);
  unsigned short* act  = (unsigned short*)(ws + ACT_OFF);
  uint4*          wgub = (uint4*)(ws + WGU_OFF);
  uint4*          wdb  = (uint4*)(ws + WDB_OFF);
  float*          part = (float*)(ws + PART_OFF);

  const bool fast = (ws_size >= WS_NEED);

  if (fast) {
    moe_convert<<<(NTOK * HIDDEN) / (256 * 8), 256, 0, stream>>>((const float4*)x, xb, cnt);
    moe_router<<<NTOK / 4, 256, 0, stream>>>(x, gw, out + OUT_ELEMS, cnt, tok, wgt, inv);
    moe_wconv_gu<<<dim3(16, 56, NE), 256, 0, stream>>>(wgu, wgub);
    moe_wconv_d<<<dim3(56, 8, NE), 256, 0, stream>>>(wd, wdb);
    moe_gateup<<<dim3(FFN / 64, 16, NE), 256, 0, stream>>>(xb, wgub, cnt, tok, act);
    moe_down<<<dim3(HIDDEN / 128, 16, NE), 256, 0, stream>>>(act, wdb, cnt, tok, wgt, part);
    moe_combine<<<NTOK, 256, 0, stream>>>(cnt, inv, (const float4*)part, (float4*)out);
  } else {
    moe_prep<<<OUT_ELEMS / (256 * 4), 256, 0, stream>>>((float4*)out, cnt);
    moe_convert<<<(NTOK * HIDDEN) / (256 * 8), 256, 0, stream>>>((const float4*)x, xb, cnt);
    moe_router<<<NTOK / 4, 256, 0, stream>>>(x, gw, out + OUT_ELEMS, cnt, tok, wgt, inv);
    moe_gateup_lg<<<dim3(FFN / 64, 16, NE), 256, 0, stream>>>(xb, wgu, cnt, tok, act);
    moe_down_lg<<<dim3(HIDDEN / 128, 16, NE), 256, 0, stream>>>((const uint4*)act, wd, cnt, tok, wgt, out);
  }
}

// Round 6
// 626.547 us; speedup vs baseline: 1.0802x; 1.0528x over previous
//
#include <hip/hip_runtime.h>
#include <hip/hip_bf16.h>
#include <stdint.h>

#define HIDDEN  1024
#define FFN     3584
#define NE      8
#define NTOK    2048
#define CAP     2048
#define OUT_ELEMS (NTOK * HIDDEN)   /* 2097152 */

/* ---- workspace layout (bytes) ---- */
#define X_OFF    0u                          /* x as bf16: 2048*1024*2 = 4 MiB   */
#define CNT_OFF  (4u*1024u*1024u)            /* 8 int counters                   */
#define TOK_OFF  (CNT_OFF + 256u)            /* token lists: 8*2048*4 = 64 KiB   */
#define WGT_OFF  (TOK_OFF + 65536u)          /* combine weights: 64 KiB          */
#define INV_OFF  (WGT_OFF + 65536u)          /* token -> 2 slot ids: 16 KiB      */
#define ACT_OFF  (INV_OFF + 16384u)          /* packed act bf16: 4096*3584*2     */
#define ACT_SZ   (4096u * 3584u * 2u)        /* 29360128                         */
#define WGU_OFF  (ACT_OFF + ACT_SZ)          /* (unused now, kept for layout)    */
#define WGU_SZ   (8u*56u*16u*16384u)         /* 117440512                        */
#define WDB_OFF  (WGU_OFF + WGU_SZ)          /* bf16 tiled down weights          */
#define WDB_SZ   (8u*8u*56u*16384u)          /* 58720256 (56 MiB)                */
#define PART_OFF (WDB_OFF + WDB_SZ)          /* fp32 partial rows: 4096*1024*4   */
#define PART_SZ  (4096u*1024u*4u)            /* 16 MiB                           */
#define WS_NEED  ((size_t)PART_OFF + (size_t)PART_SZ)

typedef __attribute__((ext_vector_type(8))) short short8;
typedef __attribute__((ext_vector_type(4))) float floatx4;

static __device__ __forceinline__ uint32_t f2bf(float f) {
  union { float f; uint32_t u; } v; v.f = f;
  return (v.u + 0x7FFFu + ((v.u >> 16) & 1u)) >> 16;   /* RNE */
}
static __device__ __forceinline__ uint32_t pack2(float lo, float hi) {
  return f2bf(lo) | (f2bf(hi) << 16);
}
union S8U { uint4 u; short8 s; };
static __device__ __forceinline__ short8 as_short8(uint4 v) { S8U x; x.u = v; return x.s; }

/* async global -> LDS, 16B per lane; LDS dest is wave-uniform base + lane*16 */
static __device__ __forceinline__ void ld_g2l16(const void* g, void* l) {
  __builtin_amdgcn_global_load_lds(
      (const __attribute__((address_space(1))) void*)g,
      (__attribute__((address_space(3))) void*)l, 16, 0, 0);
}

/* stage one 16KB A-tile + 16KB B-tile into the given LDS buffers (8 vmem/wave) */
static __device__ __forceinline__ void stage_tile(
    const char* const* aptr, const char* bptr, size_t akt, size_t bkt,
    uint4* AsB, uint4* BsB, int w)
{
#pragma unroll
  for (int it = 0; it < 4; ++it)
    ld_g2l16(aptr[it] + akt, &AsB[(w * 4 + it) * 64]);
#pragma unroll
  for (int it = 0; it < 4; ++it)
    ld_g2l16(bptr + bkt + (size_t)it * 1024u, &BsB[(w * 4 + it) * 64]);
}

/* counted-vmcnt sync helpers */
#define WAIT_VM8()  do { __builtin_amdgcn_sched_barrier(0); \
                         asm volatile("s_waitcnt vmcnt(8)" ::: "memory"); \
                         __builtin_amdgcn_sched_barrier(0); } while (0)
#define WAIT_VM16() do { __builtin_amdgcn_sched_barrier(0); \
                         asm volatile("s_waitcnt vmcnt(16)" ::: "memory"); \
                         __builtin_amdgcn_sched_barrier(0); } while (0)
#define WAIT_VM0()  do { __builtin_amdgcn_sched_barrier(0); \
                         asm volatile("s_waitcnt vmcnt(0)" ::: "memory"); \
                         __builtin_amdgcn_sched_barrier(0); } while (0)
#define WAIT_LGKM() do { asm volatile("s_waitcnt lgkmcnt(0)" ::: "memory"); } while (0)
#define BAR()       do { __builtin_amdgcn_s_barrier(); \
                         __builtin_amdgcn_sched_barrier(0); } while (0)
#define ENDBAR()    do { __builtin_amdgcn_sched_barrier(0); \
                         __builtin_amdgcn_s_barrier(); } while (0)

/* ---- zero output accumulation region + expert counters (fallback only) ---- */
__global__ __launch_bounds__(256) void moe_prep(float4* __restrict__ out4,
                                                int* __restrict__ cnt) {
  uint32_t i = blockIdx.x * 256u + threadIdx.x;
  out4[i] = make_float4(0.f, 0.f, 0.f, 0.f);
  if (blockIdx.x == 0 && threadIdx.x < NE) cnt[threadIdx.x] = 0;
}

/* ---- x fp32 -> bf16 (+ cnt zero for fast path) ---- */
__global__ __launch_bounds__(256) void moe_convert(const float4* __restrict__ x4,
                                                   uint4* __restrict__ xb,
                                                   int* __restrict__ cnt) {
  uint32_t g = blockIdx.x * 256u + threadIdx.x;
  float4 a = x4[2u*g], b = x4[2u*g + 1u];
  xb[g] = make_uint4(pack2(a.x, a.y), pack2(a.z, a.w),
                     pack2(b.x, b.y), pack2(b.z, b.w));
  if (blockIdx.x == 0 && threadIdx.x < NE) cnt[threadIdx.x] = 0;
}

/* ---- router: one wave per token ---- */
__global__ __launch_bounds__(256) void moe_router(
    const float* __restrict__ x, const float* __restrict__ gw,
    float* __restrict__ logits, int* __restrict__ cnt,
    int* __restrict__ tok, float* __restrict__ wgt, int* __restrict__ inv)
{
  const int t = blockIdx.x * 4 + (threadIdx.x >> 6);
  const int lane = threadIdx.x & 63;
  const float* xr = x + (size_t)t * HIDDEN;
  float a[NE];
#pragma unroll
  for (int e = 0; e < NE; ++e) a[e] = 0.f;
  for (int hh = 0; hh < HIDDEN / 64; ++hh) {
    float xv = xr[hh * 64 + lane];
#pragma unroll
    for (int e = 0; e < NE; ++e) a[e] += xv * gw[e * HIDDEN + hh * 64 + lane];
  }
#pragma unroll
  for (int off = 32; off > 0; off >>= 1) {
#pragma unroll
    for (int e = 0; e < NE; ++e) a[e] += __shfl_xor(a[e], off);
  }
  if (lane == 0) {
#pragma unroll
    for (int e = 0; e < NE; ++e) logits[t * NE + e] = a[e];
    int i0 = 0; float v0 = a[0];
#pragma unroll
    for (int e = 1; e < NE; ++e) if (a[e] > v0) { v0 = a[e]; i0 = e; }
    int i1 = (i0 == 0) ? 1 : 0; float v1 = a[i1];
#pragma unroll
    for (int e = 0; e < NE; ++e) if (e != i0 && a[e] > v1) { v1 = a[e]; i1 = e; }
    float w0 = 1.f / (1.f + __expf(v1 - v0));
    float w1 = 1.f - w0;
    int p0 = atomicAdd(&cnt[i0], 1); tok[i0 * CAP + p0] = t; wgt[i0 * CAP + p0] = w0;
    int p1 = atomicAdd(&cnt[i1], 1); tok[i1 * CAP + p1] = t; wgt[i1 * CAP + p1] = w1;
    inv[t * 2 + 0] = i0 * CAP + p0;
    inv[t * 2 + 1] = i1 * CAP + p1;
  }
}

/* ==== down-weight preconvert (unchanged; col-major chunk layout) ==== */
__global__ __launch_bounds__(256) void moe_wconv_d(const float* __restrict__ wd,
                                                   uint4* __restrict__ wdb) {
  const int kt = blockIdx.x, nb = blockIdx.y, e = blockIdx.z;
  const int n0 = nb * 128, k0 = kt * 64;
  const float* wB = wd + (size_t)e * FFN * HIDDEN;
  uint4* dst = wdb + ((size_t)(e * 8 + nb) * 56 + kt) * 1024;

  __shared__ float lds_f[64 * 129];

#pragma unroll
  for (int p = 0; p < 8; ++p) {
    int idx = p * 256 + threadIdx.x;
    int r   = idx >> 5;
    int lc  = (idx & 31) * 4;
    float4 v = *(const float4*)(wB + (size_t)(k0 + r) * HIDDEN + n0 + lc);
    float* d = &lds_f[r * 129 + lc];
    d[0] = v.x; d[1] = v.y; d[2] = v.z; d[3] = v.w;
  }
  __syncthreads();
#pragma unroll
  for (int p = 0; p < 4; ++p) {
    int m  = p * 256 + threadIdx.x;
    int ne = m >> 3, c8 = m & 7;
    float f[8];
#pragma unroll
    for (int kk = 0; kk < 8; ++kk) f[kk] = lds_f[(c8 * 8 + kk) * 129 + ne];
    dst[ne * 8 + (c8 ^ (ne & 7))] =
        make_uint4(pack2(f[0], f[1]), pack2(f[2], f[3]),
                   pack2(f[4], f[5]), pack2(f[6], f[7]));
  }
}

/* ==== FUSED grouped GEMM 1: act = silu(x@Wg)*(x@Wu), fp32 weights read
 *      directly, converted in-register ONCE (BM=512 = whole expert).
 * Block: 512 thr (8 waves), tile 512m x 128 logical-n x 64k per step.
 * Per step: convert B(t) regs -> Bs; issue A g2l(t); issue B fp32 loads(t+1);
 * vmcnt(16) [A landed, B(t+1) in flight]; barrier; MFMA; barrier.        ==== */
__global__ __launch_bounds__(512) void moe_gateup_f(
    const uint4* __restrict__ xb, const float* __restrict__ wgu,
    const int* __restrict__ cnt, const int* __restrict__ tok,
    unsigned short* __restrict__ act)
{
  const int e  = blockIdx.z;
  const int m0 = blockIdx.y * 512;
  const int fb = blockIdx.x;
  const int f0 = fb * 64;
  const int cn = cnt[e];
  if (m0 >= cn) return;
  int basev = 0;
#pragma unroll
  for (int i = 0; i < NE; ++i) { int ci = cnt[i]; if (i < e) basev += ci; }

  __shared__ uint4 As[4096];   /* 512 rows x 8 chunks, chunk c8 ^= row&7 : 64 KiB */
  __shared__ uint4 Bs[1024];   /* 128 cols x 8 chunks, chunk c8 ^= ne&7  : 16 KiB */

  const int tid  = threadIdx.x;
  const int lane = tid & 63;
  const int w    = tid >> 6;          /* 0..7 */
  const int q    = lane >> 4;
  const int c    = lane & 15;

  /* A gather pointers: 8 g2l per thread per step */
  const int* tokE = tok + e * CAP;
  const char* aptr[8];
#pragma unroll
  for (int it = 0; it < 8; ++it) {
    int p   = (w * 8 + it) * 64 + lane;
    int row = p >> 3, c8 = p & 7;
    int mrow = m0 + row; if (mrow >= cn) mrow = cn - 1;
    aptr[it] = (const char*)(xb + (size_t)tokE[mrow] * (HIDDEN / 8) + (c8 ^ (row & 7)));
  }

  /* B: this thread owns logical col ne, chunk rows c8b and c8b+4 */
  const int ne  = tid & 127;
  const int c8b = tid >> 7;           /* 0..3 */
  const int col = f0 + ((ne >> 6) << 5) + (ne & 31) + (((ne >> 5) & 1) ? FFN : 0);
  const float* colp = wgu + (size_t)e * HIDDEN * (2 * FFN) + col;
  const int wi0 = ne * 8 + (c8b ^ (ne & 7));
  const int wi1 = ne * 8 + ((c8b + 4) ^ (ne & 7));

  floatx4 acc[4][8];
#pragma unroll
  for (int i = 0; i < 4; ++i)
#pragma unroll
    for (int j = 0; j < 8; ++j) acc[i][j] = (floatx4){0.f, 0.f, 0.f, 0.f};

  float rv[16];
  /* prologue: B fp32 loads for step 0 (16 outstanding) */
#pragma unroll
  for (int s = 0; s < 2; ++s)
#pragma unroll
    for (int kk = 0; kk < 8; ++kk)
      rv[s * 8 + kk] = colp[(size_t)((c8b + 4 * s) * 8 + kk) * (2 * FFN)];

  const int NT = HIDDEN / 64;
  for (int kt = 0; kt < NT; ++kt) {
    WAIT_VM0();                       /* rv(kt) ready (prior A g2l already done) */
    uint4 pk0 = make_uint4(pack2(rv[0], rv[1]),  pack2(rv[2], rv[3]),
                           pack2(rv[4], rv[5]),  pack2(rv[6], rv[7]));
    uint4 pk1 = make_uint4(pack2(rv[8], rv[9]),  pack2(rv[10], rv[11]),
                           pack2(rv[12], rv[13]), pack2(rv[14], rv[15]));
    Bs[wi0] = pk0;
    Bs[wi1] = pk1;
    /* A tile for this step: 8 g2l per thread */
#pragma unroll
    for (int it = 0; it < 8; ++it)
      ld_g2l16(aptr[it] + (size_t)kt * 128u, &As[(w * 8 + it) * 64]);
    /* prefetch next B fp32 into regs */
    if (kt + 1 < NT) {
      const int kb = (kt + 1) * 64;
#pragma unroll
      for (int s = 0; s < 2; ++s)
#pragma unroll
        for (int kk = 0; kk < 8; ++kk)
          rv[s * 8 + kk] = colp[(size_t)(kb + (c8b + 4 * s) * 8 + kk) * (2 * FFN)];
      WAIT_VM16();                    /* 8 A-g2l done; 16 B loads stay in flight */
    } else {
      WAIT_VM0();
    }
    WAIT_LGKM();                      /* ds_writes visible */
    BAR();
#pragma unroll
    for (int ks = 0; ks < 2; ++ks) {
      const int kc8 = ks * 4 + q;
      short8 af[4];
#pragma unroll
      for (int i = 0; i < 4; ++i) {
        int row = w * 64 + i * 16 + c;
        af[i] = as_short8(As[row * 8 + (kc8 ^ (row & 7))]);
      }
      short8 bfr[8];
#pragma unroll
      for (int j = 0; j < 8; ++j) {
        int n = j * 16 + c;
        bfr[j] = as_short8(Bs[n * 8 + (kc8 ^ (n & 7))]);
      }
#pragma unroll
      for (int i = 0; i < 4; ++i)
#pragma unroll
        for (int j = 0; j < 8; ++j)
          acc[i][j] = __builtin_amdgcn_mfma_f32_16x16x32_bf16(af[i], bfr[j], acc[i][j], 0, 0, 0);
    }
    ENDBAR();                         /* all waves done reading As/Bs */
  }

  /* epilogue: silu(gate)*up; logical pairs (0,2)(1,3)(4,6)(5,7) */
#pragma unroll
  for (int i = 0; i < 4; ++i) {
#pragma unroll
    for (int r = 0; r < 4; ++r) {
      int m = m0 + w * 64 + i * 16 + q * 4 + r;
      if (m < cn) {
        unsigned short* arow = act + (size_t)(basev + m) * FFN;
#pragma unroll
        for (int t4 = 0; t4 < 4; ++t4) {
          const int jj = (t4 & 1) | ((t4 >> 1) << 2);     /* 0,1,4,5 */
          float g = acc[i][jj][r];
          float u = acc[i][jj + 2][r];
          float a = (g / (1.f + __expf(-g))) * u;
          arow[f0 + ((jj >> 2) << 5) + (jj & 1) * 16 + c] = (unsigned short)f2bf(a);
        }
      }
    }
  }
}

/* ==== grouped GEMM 2 (dbuf + counted-vmcnt pipeline, unchanged) ==== */
__global__ __launch_bounds__(256) void moe_down(
    const unsigned short* __restrict__ act, const uint4* __restrict__ wdb,
    const int* __restrict__ cnt, const int* __restrict__ tok,
    const float* __restrict__ wgt, float* __restrict__ part)
{
  const int e  = blockIdx.z;
  const int m0 = blockIdx.y * 128;
  const int nb = blockIdx.x;
  const int n0 = nb * 128;
  const int cn = cnt[e];
  if (m0 >= cn) return;
  int basev = 0;
#pragma unroll
  for (int i = 0; i < NE; ++i) { int ci = cnt[i]; if (i < e) basev += ci; }

  __shared__ uint4 As[2][1024];
  __shared__ uint4 Bs4[2][1024];

  const int tid  = threadIdx.x;
  const int lane = tid & 63;
  const int w    = tid >> 6;
  const int wm   = w >> 1, wn = w & 1;
  const int q    = lane >> 4;
  const int c    = lane & 15;

  const char* aptr[4];
#pragma unroll
  for (int it = 0; it < 4; ++it) {
    int p   = (w * 4 + it) * 64 + lane;
    int row = p >> 3, c8 = p & 7;
    int mrow = m0 + row; if (mrow >= cn) mrow = cn - 1;
    aptr[it] = (const char*)act +
               ((size_t)(basev + mrow) * FFN + (size_t)((c8 ^ (row & 7)) * 8)) * 2u;
  }
  const char* bptr = (const char*)wdb + ((size_t)(e * 8 + nb) * 56) * 16384u
                   + (size_t)w * 4096u + (size_t)lane * 16u;

  floatx4 acc[4][4];
#pragma unroll
  for (int i = 0; i < 4; ++i)
#pragma unroll
    for (int j = 0; j < 4; ++j) acc[i][j] = (floatx4){0.f, 0.f, 0.f, 0.f};

  const int NT = FFN / 64;
  stage_tile(aptr, bptr, 0, 0, As[0], Bs4[0], w);
  int cur = 0;
  for (int kt = 0; kt < NT; ++kt) {
    if (kt + 1 < NT) {
      stage_tile(aptr, bptr, (size_t)(kt + 1) * 128u, (size_t)(kt + 1) * 16384u,
                 As[cur ^ 1], Bs4[cur ^ 1], w);
      WAIT_VM8();
    } else {
      WAIT_VM0();
    }
    BAR();
    const uint4* Asc = As[cur];
    const uint4* Bsc = Bs4[cur];
#pragma unroll
    for (int ks = 0; ks < 2; ++ks) {
      const int kc8 = ks * 4 + q;
      short8 af[4];
#pragma unroll
      for (int i = 0; i < 4; ++i) {
        int row = wm * 64 + i * 16 + c;
        af[i] = as_short8(Asc[row * 8 + (kc8 ^ (row & 7))]);
      }
      short8 bfr[4];
#pragma unroll
      for (int j = 0; j < 4; ++j) {
        int n = wn * 64 + j * 16 + c;
        bfr[j] = as_short8(Bsc[n * 8 + (kc8 ^ (n & 7))]);
      }
#pragma unroll
      for (int i = 0; i < 4; ++i)
#pragma unroll
        for (int j = 0; j < 4; ++j)
          acc[i][j] = __builtin_amdgcn_mfma_f32_16x16x32_bf16(af[i], bfr[j], acc[i][j], 0, 0, 0);
    }
    ENDBAR();
    cur ^= 1;
  }

#pragma unroll
  for (int i = 0; i < 4; ++i) {
#pragma unroll
    for (int r = 0; r < 4; ++r) {
      int m = m0 + wm * 64 + i * 16 + q * 4 + r;
      if (m < cn) {
        float  wg   = wgt[e * CAP + m];
        float* prow = part + (size_t)(basev + m) * HIDDEN + n0 + wn * 64 + c;
#pragma unroll
        for (int j = 0; j < 4; ++j)
          prow[j * 16] = acc[i][j][r] * wg;
      }
    }
  }
}

/* ==== combine: out[t] = part[slot0(t)] + part[slot1(t)] ==== */
__global__ __launch_bounds__(256) void moe_combine(
    const int* __restrict__ cnt, const int* __restrict__ inv,
    const float4* __restrict__ part4, float4* __restrict__ out4)
{
  const int t  = blockIdx.x;
  const int s0 = inv[2 * t], s1 = inv[2 * t + 1];
  const int e0 = s0 >> 11, e1 = s1 >> 11;          /* CAP = 2048 */
  int b0 = 0, b1 = 0;
#pragma unroll
  for (int i = 0; i < NE; ++i) {
    int ci = cnt[i];
    if (i < e0) b0 += ci;
    if (i < e1) b1 += ci;
  }
  const size_t r0 = (size_t)(b0 + (s0 & (CAP - 1))) * 256u;
  const size_t r1 = (size_t)(b1 + (s1 & (CAP - 1))) * 256u;
  const int i = threadIdx.x;
  float4 a = part4[r0 + i];
  float4 b = part4[r1 + i];
  out4[(size_t)t * 256u + i] = make_float4(a.x + b.x, a.y + b.y, a.z + b.z, a.w + b.w);
}

/* ==== legacy fallback GEMMs (used only if workspace too small) ==== */
__global__ __launch_bounds__(256) void moe_gateup_lg(
    const uint4* __restrict__ xb, const float* __restrict__ wgu,
    const int* __restrict__ cnt, const int* __restrict__ tok,
    unsigned short* __restrict__ act)
{
  const int e  = blockIdx.z;
  const int m0 = blockIdx.y * 128;
  const int f0 = blockIdx.x * 64;
  const int cn = cnt[e];
  if (m0 >= cn) return;
  int basev = 0;
#pragma unroll
  for (int i = 0; i < NE; ++i) { int ci = cnt[i]; if (i < e) basev += ci; }

  __shared__ uint4    As[1024];
  __shared__ uint32_t Bs[4096];

  const int tid  = threadIdx.x;
  const int lane = tid & 63;
  const int w    = tid >> 6;
  const int wm   = w >> 1, wn = w & 1;
  const int q    = lane >> 4;
  const int c    = lane & 15;

  floatx4 acc[4][4];
#pragma unroll
  for (int i = 0; i < 4; ++i)
#pragma unroll
    for (int j = 0; j < 4; ++j) acc[i][j] = (floatx4){0.f, 0.f, 0.f, 0.f};

  const float* wB  = wgu + (size_t)e * HIDDEN * (2 * FFN);
  const int* tokE  = tok + e * CAP;

  for (int kt = 0; kt < HIDDEN / 64; ++kt) {
    const int k0 = kt * 64;
    __syncthreads();
#pragma unroll
    for (int it = 0; it < 4; ++it) {
      int cid = it * 256 + tid;
      int row = cid >> 3, c8 = cid & 7;
      int mrow = m0 + row; if (mrow >= cn) mrow = cn - 1;
      int tk = tokE[mrow];
      As[row * 8 + (c8 ^ (row & 7))] = xb[(size_t)tk * (HIDDEN / 8) + (k0 >> 3) + c8];
    }
#pragma unroll
    for (int it = 0; it < 4; ++it) {
      int mid = it * 256 + tid;
      int kp = mid >> 5;
      int n  = (mid & 31) * 4;
      int col = f0 + ((n >> 6) << 5) + (n & 31) + (((n >> 5) & 1) ? FFN : 0);
      const float* src = wB + (size_t)(k0 + 2 * kp) * (2 * FFN) + col;
      float4 r0 = *(const float4*)src;
      float4 r1 = *(const float4*)(src + 2 * FFN);
      int widx = kp * 128 + (n ^ (((kp >> 2) & 1) << 4));
      *(uint4*)&Bs[widx] = make_uint4(pack2(r0.x, r1.x), pack2(r0.y, r1.y),
                                      pack2(r0.z, r1.z), pack2(r0.w, r1.w));
    }
    __syncthreads();
#pragma unroll
    for (int ks = 0; ks < 2; ++ks) {
      short8 af[4];
#pragma unroll
      for (int i = 0; i < 4; ++i) {
        int row = wm * 64 + i * 16 + c;
        int kc8 = ks * 4 + q;
        af[i] = as_short8(As[row * 8 + (kc8 ^ (row & 7))]);
      }
      short8 bfr[4];
#pragma unroll
      for (int j = 0; j < 4; ++j) {
        int n  = wn * 64 + j * 16 + c;
        int kp = ks * 16 + q * 4;
        int nn = n ^ ((q & 1) << 4);
        bfr[j] = as_short8(make_uint4(Bs[(kp + 0) * 128 + nn], Bs[(kp + 1) * 128 + nn],
                                      Bs[(kp + 2) * 128 + nn], Bs[(kp + 3) * 128 + nn]));
      }
#pragma unroll
      for (int i = 0; i < 4; ++i)
#pragma unroll
        for (int j = 0; j < 4; ++j)
          acc[i][j] = __builtin_amdgcn_mfma_f32_16x16x32_bf16(af[i], bfr[j], acc[i][j], 0, 0, 0);
    }
  }

#pragma unroll
  for (int i = 0; i < 4; ++i) {
#pragma unroll
    for (int r = 0; r < 4; ++r) {
      int m = m0 + wm * 64 + i * 16 + q * 4 + r;
      if (m < cn) {
#pragma unroll
        for (int j = 0; j < 2; ++j) {
          float g = acc[i][j][r];
          float u = acc[i][j + 2][r];
          float a = (g / (1.f + __expf(-g))) * u;
          act[(size_t)(basev + m) * FFN + (f0 + wn * 32 + j * 16 + c)] = (unsigned short)f2bf(a);
        }
      }
    }
  }
}

__global__ __launch_bounds__(256) void moe_down_lg(
    const uint4* __restrict__ actc, const float* __restrict__ wd,
    const int* __restrict__ cnt, const int* __restrict__ tok,
    const float* __restrict__ wgt, float* __restrict__ out)
{
  const int e  = blockIdx.z;
  const int m0 = blockIdx.y * 128;
  const int n0 = blockIdx.x * 128;
  const int cn = cnt[e];
  if (m0 >= cn) return;
  int basev = 0;
#pragma unroll
  for (int i = 0; i < NE; ++i) { int ci = cnt[i]; if (i < e) basev += ci; }

  __shared__ uint4    As[1024];
  __shared__ uint32_t Bs[4096];

  const int tid  = threadIdx.x;
  const int lane = tid & 63;
  const int w    = tid >> 6;
  const int wm   = w >> 1, wn = w & 1;
  const int q    = lane >> 4;
  const int c    = lane & 15;

  floatx4 acc[4][4];
#pragma unroll
  for (int i = 0; i < 4; ++i)
#pragma unroll
    for (int j = 0; j < 4; ++j) acc[i][j] = (floatx4){0.f, 0.f, 0.f, 0.f};

  const float* wB = wd + (size_t)e * FFN * HIDDEN;

  for (int kt = 0; kt < FFN / 64; ++kt) {
    const int k0 = kt * 64;
    __syncthreads();
#pragma unroll
    for (int it = 0; it < 4; ++it) {
      int cid = it * 256 + tid;
      int row = cid >> 3, c8 = cid & 7;
      int mrow = m0 + row; if (mrow >= cn) mrow = cn - 1;
      As[row * 8 + (c8 ^ (row & 7))] =
          actc[(size_t)(basev + mrow) * (FFN / 8) + (k0 >> 3) + c8];
    }
#pragma unroll
    for (int it = 0; it < 4; ++it) {
      int mid = it * 256 + tid;
      int kp = mid >> 5;
      int n  = (mid & 31) * 4;
      int col = n0 + n;
      const float* src = wB + (size_t)(k0 + 2 * kp) * HIDDEN + col;
      float4 r0 = *(const float4*)src;
      float4 r1 = *(const float4*)(src + HIDDEN);
      int widx = kp * 128 + (n ^ (((kp >> 2) & 1) << 4));
      *(uint4*)&Bs[widx] = make_uint4(pack2(r0.x, r1.x), pack2(r0.y, r1.y),
                                      pack2(r0.z, r1.z), pack2(r0.w, r1.w));
    }
    __syncthreads();
#pragma unroll
    for (int ks = 0; ks < 2; ++ks) {
      short8 af[4];
#pragma unroll
      for (int i = 0; i < 4; ++i) {
        int row = wm * 64 + i * 16 + c;
        int kc8 = ks * 4 + q;
        af[i] = as_short8(As[row * 8 + (kc8 ^ (row & 7))]);
      }
      short8 bfr[4];
#pragma unroll
      for (int j = 0; j < 4; ++j) {
        int n  = wn * 64 + j * 16 + c;
        int kp = ks * 16 + q * 4;
        int nn = n ^ ((q & 1) << 4);
        bfr[j] = as_short8(make_uint4(Bs[(kp + 0) * 128 + nn], Bs[(kp + 1) * 128 + nn],
                                      Bs[(kp + 2) * 128 + nn], Bs[(kp + 3) * 128 + nn]));
      }
#pragma unroll
      for (int i = 0; i < 4; ++i)
#pragma unroll
        for (int j = 0; j < 4; ++j)
          acc[i][j] = __builtin_amdgcn_mfma_f32_16x16x32_bf16(af[i], bfr[j], acc[i][j], 0, 0, 0);
    }
  }

#pragma unroll
  for (int i = 0; i < 4; ++i) {
#pragma unroll
    for (int r = 0; r < 4; ++r) {
      int m = m0 + wm * 64 + i * 16 + q * 4 + r;
      if (m < cn) {
        int   t  = tok[e * CAP + m];
        float wg = wgt[e * CAP + m];
        float* orow = out + (size_t)t * HIDDEN + n0 + wn * 64 + c;
#pragma unroll
        for (int j = 0; j < 4; ++j)
          atomicAdd(orow + j * 16, acc[i][j][r] * wg);
      }
    }
  }
}

extern "C" void kernel_launch(void* const* d_in, const int* in_sizes, int n_in,
                              void* d_out, int out_size, void* d_ws, size_t ws_size,
                              hipStream_t stream)
{
  (void)in_sizes; (void)n_in; (void)out_size;
  const float* x   = (const float*)d_in[0];
  const float* gw  = (const float*)d_in[1];
  const float* wgu = (const float*)d_in[2];
  const float* wd  = (const float*)d_in[3];
  float* out = (float*)d_out;
  char*  ws  = (char*)d_ws;

  uint4*          xb   = (uint4*)(ws + X_OFF);
  int*            cnt  = (int*)(ws + CNT_OFF);
  int*            tok  = (int*)(ws + TOK_OFF);
  float*          wgt  = (float*)(ws + WGT_OFF);
  int*            inv  = (int*)(ws + INV_OFF);
  unsigned short* act  = (unsigned short*)(ws + ACT_OFF);
  uint4*          wdb  = (uint4*)(ws + WDB_OFF);
  float*          part = (float*)(ws + PART_OFF);

  const bool fast = (ws_size >= WS_NEED);

  if (fast) {
    moe_convert<<<(NTOK * HIDDEN) / (256 * 8), 256, 0, stream>>>((const float4*)x, xb, cnt);
    moe_router<<<NTOK / 4, 256, 0, stream>>>(x, gw, out + OUT_ELEMS, cnt, tok, wgt, inv);
    moe_wconv_d<<<dim3(56, 8, NE), 256, 0, stream>>>(wd, wdb);
    moe_gateup_f<<<dim3(FFN / 64, CAP / 512, NE), 512, 0, stream>>>(xb, wgu, cnt, tok, act);
    moe_down<<<dim3(HIDDEN / 128, 16, NE), 256, 0, stream>>>(act, wdb, cnt, tok, wgt, part);
    moe_combine<<<NTOK, 256, 0, stream>>>(cnt, inv, (const float4*)part, (float4*)out);
  } else {
    moe_prep<<<OUT_ELEMS / (256 * 4), 256, 0, stream>>>((float4*)out, cnt);
    moe_convert<<<(NTOK * HIDDEN) / (256 * 8), 256, 0, stream>>>((const float4*)x, xb, cnt);
    moe_router<<<NTOK / 4, 256, 0, stream>>>(x, gw, out + OUT_ELEMS, cnt, tok, wgt, inv);
    moe_gateup_lg<<<dim3(FFN / 64, 16, NE), 256, 0, stream>>>(xb, wgu, cnt, tok, act);
    moe_down_lg<<<dim3(HIDDEN / 128, 16, NE), 256, 0, stream>>>((const uint4*)act, wd, cnt, tok, wgt, out);
  }
}